// Round 1
// 504.059 us; speedup vs baseline: 1.0504x; 1.0504x over previous
//
#include <hip/hip_runtime.h>

// 3-layer GAT (PyG GATConv) on MI355X.
// CSR build: count_rank (atomicAdd returns in-bucket rank) -> scan -> fill
// (pure scatter, no atomics, esrc only; edst never materialized).
// Per layer: gemm_att (H + attention dots) -> gat_aggr (node-parallel fused
// softmax + gather-FMA aggregation, register edge stash, no atomics).

constexpr int BLOCK = 256;

__device__ __forceinline__ float llrelu(float x) { return x >= 0.f ? x : 0.2f * x; }

__global__ void zero_int_kernel(int* __restrict__ p, int count) {
    int i = blockIdx.x * blockDim.x + threadIdx.x;
    int stride = gridDim.x * blockDim.x;
    for (; i < count; i += stride) p[i] = 0;
}

__global__ void zero_float_kernel(float* __restrict__ p, int count) {
    int i = blockIdx.x * blockDim.x + threadIdx.x;
    if (i < count) p[i] = 0.f;
}

// counts[d]++ per edge; the atomic's return value IS the edge's rank within
// its dst bucket (arrival order; any stable-enough order is valid for CSR).
__global__ void count_rank_kernel(const int* __restrict__ dst, int E,
                                  int* __restrict__ counts, int* __restrict__ rank) {
    int i = blockIdx.x * blockDim.x + threadIdx.x;
    int stride = gridDim.x * blockDim.x;
    for (; i < E; i += stride) rank[i] = atomicAdd(&counts[dst[i]], 1);
}

__global__ void scan_phase1(const int* __restrict__ counts, int n,
                            int* __restrict__ excl, int* __restrict__ block_sums) {
    __shared__ int s[1024];
    int tid = threadIdx.x;
    int gid = blockIdx.x * 1024 + tid;
    int v = (gid < n) ? counts[gid] : 0;
    s[tid] = v;
    for (int off = 1; off < 1024; off <<= 1) {
        __syncthreads();
        int t = (tid >= off) ? s[tid - off] : 0;
        __syncthreads();
        s[tid] += t;
    }
    __syncthreads();
    if (gid < n) excl[gid] = s[tid] - v;
    if (tid == 1023) block_sums[blockIdx.x] = s[tid];
}

__global__ void scan_phase2(int* __restrict__ block_sums, int nb) {
    __shared__ int s[1024];
    int tid = threadIdx.x;
    int v = (tid < nb) ? block_sums[tid] : 0;
    s[tid] = v;
    for (int off = 1; off < 1024; off <<= 1) {
        __syncthreads();
        int t = (tid >= off) ? s[tid - off] : 0;
        __syncthreads();
        s[tid] += t;
    }
    __syncthreads();
    if (tid < nb) block_sums[tid] = s[tid] - v;  // exclusive
}

__global__ void scan_phase3(int* __restrict__ row_start, const int* __restrict__ block_sums,
                            int n, int E) {
    int gid = blockIdx.x * blockDim.x + threadIdx.x;
    if (gid < n) row_start[gid] += block_sums[gid >> 10];
    if (gid == 0) row_start[n] = E;
}

// Pure scatter: slot = row_start[dst] + rank. No atomics, single 4B payload.
__global__ void fill_kernel(const int* __restrict__ src, const int* __restrict__ dst,
                            const int* __restrict__ rank, int E,
                            const int* __restrict__ row_start, int* __restrict__ esrc) {
    int i = blockIdx.x * blockDim.x + threadIdx.x;
    int stride = gridDim.x * blockDim.x;
    for (; i < E; i += stride) esrc[row_start[dst[i]] + rank[i]] = src[i];
}

// H = relu?(X) @ W, plus fused attention dots Ssrc = H.a_src, Sdst = H.a_dst.
template <int FIN, int FOUT, bool RELU_IN>
__global__ void gemm_att_kernel(const float* __restrict__ X, const float* __restrict__ W,
                                const float* __restrict__ asrc, const float* __restrict__ adst,
                                float* __restrict__ H, float* __restrict__ Ssrc,
                                float* __restrict__ Sdst, int n) {
    __shared__ float Ws[FIN * FOUT];
    int tid = threadIdx.x;
    for (int i = tid; i < FIN * FOUT; i += BLOCK) Ws[i] = W[i];
    __syncthreads();

    int node = blockIdx.x * (BLOCK / FOUT) + tid / FOUT;
    int col = tid % FOUT;
    if (node >= n) return;

    const float4* xr4 = (const float4*)(X + (size_t)node * FIN);
    float acc = 0.f;
#pragma unroll
    for (int k4 = 0; k4 < FIN / 4; ++k4) {
        float4 v = xr4[k4];
        if (RELU_IN) {
            v.x = fmaxf(v.x, 0.f); v.y = fmaxf(v.y, 0.f);
            v.z = fmaxf(v.z, 0.f); v.w = fmaxf(v.w, 0.f);
        }
        acc = fmaf(v.x, Ws[(4 * k4 + 0) * FOUT + col], acc);
        acc = fmaf(v.y, Ws[(4 * k4 + 1) * FOUT + col], acc);
        acc = fmaf(v.z, Ws[(4 * k4 + 2) * FOUT + col], acc);
        acc = fmaf(v.w, Ws[(4 * k4 + 3) * FOUT + col], acc);
    }
    H[(size_t)node * FOUT + col] = acc;

    float vs = acc * asrc[col];
    float vd = acc * adst[col];
#pragma unroll
    for (int off = FOUT / 2; off > 0; off >>= 1) {
        vs += __shfl_xor(vs, off, FOUT);
        vd += __shfl_xor(vd, off, FOUT);
    }
    if (col == 0) {
        Ssrc[node] = vs;
        Sdst[node] = vd;
    }
}

// Node-parallel fused softmax + aggregation. One F-lane group per node:
// pass1 logits (register stash, K slots/lane => deg<=K*F fast path),
// pass2 exp+sum, pass3 shuffle-broadcast weighted gather-FMA over H rows.
// Overflow rows (deg > K*F) take a correct recompute path (Ssrc is L2-hot).
// No atomics, no edge-weight buffer, no edst.
template <int F, int K, bool WITH_BIAS>
__global__ void gat_aggr_kernel(const float* __restrict__ H, const float* __restrict__ Ssrc,
                                const float* __restrict__ Sdst, const int* __restrict__ row_start,
                                const int* __restrict__ esrc, const float* __restrict__ bias,
                                float* __restrict__ OUT, int n) {
    int tid = threadIdx.x;
    int node = blockIdx.x * (BLOCK / F) + tid / F;
    int lane = tid % F;
    if (node >= n) return;

    int rs = row_start[node];
    int deg = row_start[node + 1] - rs;
    float sdi = Sdst[node];
    float selft = llrelu(Ssrc[node] + sdi);

    int sreg[K];
    float wreg[K];

    // pass 1: logits -> stash, running max (self-loop included, PyG semantics)
    float m = selft;
#pragma unroll
    for (int k = 0; k < K; ++k) {
        int j = k * F + lane;
        if (j < deg) {
            int s = esrc[rs + j];
            float t = llrelu(Ssrc[s] + sdi);
            sreg[k] = s;
            wreg[k] = t;
            m = fmaxf(m, t);
        }
    }
    for (int j = K * F + lane; j < deg; j += F)  // overflow (deg > K*F): rare
        m = fmaxf(m, llrelu(Ssrc[esrc[rs + j]] + sdi));
#pragma unroll
    for (int off = F / 2; off > 0; off >>= 1) m = fmaxf(m, __shfl_xor(m, off, F));

    // pass 2: exp -> stash, running sum
    float selfw = __expf(selft - m);
    float l = (lane == 0) ? selfw : 0.f;
#pragma unroll
    for (int k = 0; k < K; ++k) {
        int j = k * F + lane;
        if (j < deg) {
            float e = __expf(wreg[k] - m);
            wreg[k] = e;
            l += e;
        }
    }
    for (int j = K * F + lane; j < deg; j += F)
        l += __expf(llrelu(Ssrc[esrc[rs + j]] + sdi) - m);
#pragma unroll
    for (int off = F / 2; off > 0; off >>= 1) l += __shfl_xor(l, off, F);
    float winv = 1.f / l;

    // pass 3: acc = sum_j w_j * H[s_j][lane]  (shuffle-broadcast of stash)
    float acc = selfw * H[(size_t)node * F + lane];
#pragma unroll
    for (int k = 0; k < K; ++k) {
        int j0 = k * F;
        if (j0 < deg) {
            int cnt = min(F, deg - j0);
            float wme = wreg[k];
            int sme = sreg[k];
            for (int jj = 0; jj < cnt; ++jj) {
                float wj = __shfl(wme, jj, F);
                int sj = __shfl(sme, jj, F);
                acc = fmaf(wj, H[(size_t)sj * F + lane], acc);
            }
        }
    }
    for (int j = K * F; j < deg; ++j) {  // overflow: all lanes recompute w_j
        int s = esrc[rs + j];
        float wj = __expf(llrelu(Ssrc[s] + sdi) - m);
        acc = fmaf(wj, H[(size_t)s * F + lane], acc);
    }

    acc *= winv;
    if (WITH_BIAS) acc += bias[lane];
    OUT[(size_t)node * F + lane] = acc;
}

// Sum OUT3 over nodes into facc[32].
__global__ void mean_kernel(const float* __restrict__ B, float* __restrict__ facc, int n) {
    __shared__ float s[32];
    int lane = threadIdx.x & 31, row = threadIdx.x >> 5;
    float a = 0.f;
    for (int node = blockIdx.x * 8 + row; node < n; node += gridDim.x * 8)
        a += B[(size_t)node * 32 + lane];
    if (threadIdx.x < 32) s[threadIdx.x] = 0.f;
    __syncthreads();
    atomicAdd(&s[lane], a);
    __syncthreads();
    if (threadIdx.x < 32) atomicAdd(&facc[threadIdx.x], s[threadIdx.x]);
}

__global__ void finalize_kernel(const float* __restrict__ facc, const float* __restrict__ b,
                                const float* __restrict__ tdp, const float* __restrict__ cansup,
                                float* __restrict__ out, int n) {
    int f = threadIdx.x;
    if (f < 32) {
        float td = tdp[0] * cansup[0];
        out[f] = (facc[f] / (float)n + b[f]) * td;
    }
}

extern "C" void kernel_launch(void* const* d_in, const int* in_sizes, int n_in,
                              void* d_out, int out_size, void* d_ws, size_t ws_size,
                              hipStream_t stream) {
    const float* x      = (const float*)d_in[0];
    const int* eidx     = (const int*)d_in[1];
    const float* W1     = (const float*)d_in[2];
    const float* as1    = (const float*)d_in[3];
    const float* ad1    = (const float*)d_in[4];
    const float* b1     = (const float*)d_in[5];
    const float* W2     = (const float*)d_in[6];
    const float* as2    = (const float*)d_in[7];
    const float* ad2    = (const float*)d_in[8];
    const float* b2     = (const float*)d_in[9];
    const float* W3     = (const float*)d_in[10];
    const float* as3    = (const float*)d_in[11];
    const float* ad3    = (const float*)d_in[12];
    const float* b3     = (const float*)d_in[13];
    const float* tdp    = (const float*)d_in[14];
    const float* cansup = (const float*)d_in[15];

    const int n = in_sizes[0] / 64;   // 100000 nodes
    const int E = in_sizes[1] / 2;    // 1600000 edges
    const int* srcp = eidx;
    const int* dstp = eidx + E;

    char* ws = (char*)d_ws;
    size_t off = 0;
    auto alloc = [&](size_t bytes) -> void* {
        void* p = ws + off;
        off += (bytes + 255) & ~(size_t)255;
        return p;
    };
    float* A      = (float*)alloc((size_t)n * 64 * sizeof(float));  // H
    float* B      = (float*)alloc((size_t)n * 64 * sizeof(float));  // layer out
    float* ssrc   = (float*)alloc((size_t)n * sizeof(float));
    float* sdst   = (float*)alloc((size_t)n * sizeof(float));
    int*   counts = (int*)alloc((size_t)n * sizeof(int));
    int*   rowst  = (int*)alloc((size_t)(n + 1) * sizeof(int));
    int*   bsums  = (int*)alloc(1024 * sizeof(int));
    int*   esrc   = (int*)alloc((size_t)E * sizeof(int));
    int*   rank   = (int*)alloc((size_t)E * sizeof(int));
    float* facc   = (float*)alloc(64 * sizeof(float));

    // ---- CSR build (once; graph shared across layers) ----
    zero_int_kernel<<<(n + 255) / 256, 256, 0, stream>>>(counts, n);
    zero_float_kernel<<<1, 64, 0, stream>>>(facc, 32);
    count_rank_kernel<<<2048, 256, 0, stream>>>(dstp, E, counts, rank);
    int nb = (n + 1023) / 1024;
    scan_phase1<<<nb, 1024, 0, stream>>>(counts, n, rowst, bsums);
    scan_phase2<<<1, 1024, 0, stream>>>(bsums, nb);
    scan_phase3<<<(n + 255) / 256, 256, 0, stream>>>(rowst, bsums, n, E);
    fill_kernel<<<2048, 256, 0, stream>>>(srcp, dstp, rank, E, rowst, esrc);

    // ---- layer 1: 64 -> 64 (ReLU folded into layer-2 gemm load) ----
    gemm_att_kernel<64, 64, false><<<(n + 3) / 4, BLOCK, 0, stream>>>(x, W1, as1, ad1, A, ssrc, sdst, n);
    gat_aggr_kernel<64, 2, true><<<(n + 3) / 4, BLOCK, 0, stream>>>(A, ssrc, sdst, rowst, esrc, b1, B, n);

    // ---- layer 2: 64 -> 32 (ReLU folded into layer-3 gemm load) ----
    gemm_att_kernel<64, 32, true><<<(n + 7) / 8, BLOCK, 0, stream>>>(B, W2, as2, ad2, A, ssrc, sdst, n);
    gat_aggr_kernel<32, 4, true><<<(n + 7) / 8, BLOCK, 0, stream>>>(A, ssrc, sdst, rowst, esrc, b2, B, n);

    // ---- layer 3: 32 -> 32, then global mean ----
    gemm_att_kernel<32, 32, true><<<(n + 7) / 8, BLOCK, 0, stream>>>(B, W3, as3, ad3, A, ssrc, sdst, n);
    gat_aggr_kernel<32, 4, false><<<(n + 7) / 8, BLOCK, 0, stream>>>(A, ssrc, sdst, rowst, esrc, nullptr, B, n);
    mean_kernel<<<1024, 256, 0, stream>>>(B, facc, n);
    finalize_kernel<<<1, 64, 0, stream>>>(facc, b3, tdp, cansup, (float*)d_out, n);
}

// Round 2
// 405.172 us; speedup vs baseline: 1.3067x; 1.2441x over previous
//
#include <hip/hip_runtime.h>

// 3-layer GAT (PyG GATConv) on MI355X.
// CSR build: count_rank (atomicAdd returns in-bucket rank) -> scan -> fill
// (pure scatter, no atomics, esrc only; edst never materialized).
// Per layer: gemm_att (H + attention dots) -> gat_aggr (node-parallel fused
// softmax + gather-FMA aggregation; pass 3 issues 8 independent H-row
// gathers per batch for memory-level parallelism).

constexpr int BLOCK = 256;

__device__ __forceinline__ float llrelu(float x) { return x >= 0.f ? x : 0.2f * x; }

__global__ void zero_int_kernel(int* __restrict__ p, int count) {
    int i = blockIdx.x * blockDim.x + threadIdx.x;
    int stride = gridDim.x * blockDim.x;
    for (; i < count; i += stride) p[i] = 0;
}

__global__ void zero_float_kernel(float* __restrict__ p, int count) {
    int i = blockIdx.x * blockDim.x + threadIdx.x;
    if (i < count) p[i] = 0.f;
}

// counts[d]++ per edge; the atomic's return value IS the edge's rank within
// its dst bucket (arrival order; any stable-enough order is valid for CSR).
__global__ void count_rank_kernel(const int* __restrict__ dst, int E,
                                  int* __restrict__ counts, int* __restrict__ rank) {
    int i = blockIdx.x * blockDim.x + threadIdx.x;
    int stride = gridDim.x * blockDim.x;
    for (; i < E; i += stride) rank[i] = atomicAdd(&counts[dst[i]], 1);
}

__global__ void scan_phase1(const int* __restrict__ counts, int n,
                            int* __restrict__ excl, int* __restrict__ block_sums) {
    __shared__ int s[1024];
    int tid = threadIdx.x;
    int gid = blockIdx.x * 1024 + tid;
    int v = (gid < n) ? counts[gid] : 0;
    s[tid] = v;
    for (int off = 1; off < 1024; off <<= 1) {
        __syncthreads();
        int t = (tid >= off) ? s[tid - off] : 0;
        __syncthreads();
        s[tid] += t;
    }
    __syncthreads();
    if (gid < n) excl[gid] = s[tid] - v;
    if (tid == 1023) block_sums[blockIdx.x] = s[tid];
}

__global__ void scan_phase2(int* __restrict__ block_sums, int nb) {
    __shared__ int s[1024];
    int tid = threadIdx.x;
    int v = (tid < nb) ? block_sums[tid] : 0;
    s[tid] = v;
    for (int off = 1; off < 1024; off <<= 1) {
        __syncthreads();
        int t = (tid >= off) ? s[tid - off] : 0;
        __syncthreads();
        s[tid] += t;
    }
    __syncthreads();
    if (tid < nb) block_sums[tid] = s[tid] - v;  // exclusive
}

__global__ void scan_phase3(int* __restrict__ row_start, const int* __restrict__ block_sums,
                            int n, int E) {
    int gid = blockIdx.x * blockDim.x + threadIdx.x;
    if (gid < n) row_start[gid] += block_sums[gid >> 10];
    if (gid == 0) row_start[n] = E;
}

// Pure scatter: slot = row_start[dst] + rank. No atomics, single 4B payload.
__global__ void fill_kernel(const int* __restrict__ src, const int* __restrict__ dst,
                            const int* __restrict__ rank, int E,
                            const int* __restrict__ row_start, int* __restrict__ esrc) {
    int i = blockIdx.x * blockDim.x + threadIdx.x;
    int stride = gridDim.x * blockDim.x;
    for (; i < E; i += stride) esrc[row_start[dst[i]] + rank[i]] = src[i];
}

// H = relu?(X) @ W, plus fused attention dots Ssrc = H.a_src, Sdst = H.a_dst.
template <int FIN, int FOUT, bool RELU_IN>
__global__ void gemm_att_kernel(const float* __restrict__ X, const float* __restrict__ W,
                                const float* __restrict__ asrc, const float* __restrict__ adst,
                                float* __restrict__ H, float* __restrict__ Ssrc,
                                float* __restrict__ Sdst, int n) {
    __shared__ float Ws[FIN * FOUT];
    int tid = threadIdx.x;
    for (int i = tid; i < FIN * FOUT; i += BLOCK) Ws[i] = W[i];
    __syncthreads();

    int node = blockIdx.x * (BLOCK / FOUT) + tid / FOUT;
    int col = tid % FOUT;
    if (node >= n) return;

    const float4* xr4 = (const float4*)(X + (size_t)node * FIN);
    float acc = 0.f;
#pragma unroll
    for (int k4 = 0; k4 < FIN / 4; ++k4) {
        float4 v = xr4[k4];
        if (RELU_IN) {
            v.x = fmaxf(v.x, 0.f); v.y = fmaxf(v.y, 0.f);
            v.z = fmaxf(v.z, 0.f); v.w = fmaxf(v.w, 0.f);
        }
        acc = fmaf(v.x, Ws[(4 * k4 + 0) * FOUT + col], acc);
        acc = fmaf(v.y, Ws[(4 * k4 + 1) * FOUT + col], acc);
        acc = fmaf(v.z, Ws[(4 * k4 + 2) * FOUT + col], acc);
        acc = fmaf(v.w, Ws[(4 * k4 + 3) * FOUT + col], acc);
    }
    H[(size_t)node * FOUT + col] = acc;

    float vs = acc * asrc[col];
    float vd = acc * adst[col];
#pragma unroll
    for (int off = FOUT / 2; off > 0; off >>= 1) {
        vs += __shfl_xor(vs, off, FOUT);
        vd += __shfl_xor(vd, off, FOUT);
    }
    if (col == 0) {
        Ssrc[node] = vs;
        Sdst[node] = vd;
    }
}

// Node-parallel fused softmax + aggregation. One F-lane group per node:
// pass1 logits (register stash, K slots/lane => deg<=K*F fast path),
// pass2 exp+sum, pass3 shuffle-broadcast weighted gather-FMA over H rows,
// batched 8-deep so 8 row-gathers are in flight per wave (latency hiding).
// Tail slots clamp to the batch's first slot with weight 0: same-address
// L1-hit load, group-uniform predicate (no divergence, no wasted HBM).
// Overflow rows (deg > K*F) take a correct recompute path.
template <int F, int K, bool WITH_BIAS>
__global__ void gat_aggr_kernel(const float* __restrict__ H, const float* __restrict__ Ssrc,
                                const float* __restrict__ Sdst, const int* __restrict__ row_start,
                                const int* __restrict__ esrc, const float* __restrict__ bias,
                                float* __restrict__ OUT, int n) {
    int tid = threadIdx.x;
    int node = blockIdx.x * (BLOCK / F) + tid / F;
    int lane = tid % F;
    if (node >= n) return;

    int rs = row_start[node];
    int deg = row_start[node + 1] - rs;
    float sdi = Sdst[node];
    float selft = llrelu(Ssrc[node] + sdi);

    int sreg[K];
    float wreg[K];

    // pass 1: logits -> stash, running max (self-loop included, PyG semantics)
    float m = selft;
#pragma unroll
    for (int k = 0; k < K; ++k) {
        int j = k * F + lane;
        if (j < deg) {
            int s = esrc[rs + j];
            float t = llrelu(Ssrc[s] + sdi);
            sreg[k] = s;
            wreg[k] = t;
            m = fmaxf(m, t);
        }
    }
    for (int j = K * F + lane; j < deg; j += F)  // overflow (deg > K*F): rare
        m = fmaxf(m, llrelu(Ssrc[esrc[rs + j]] + sdi));
#pragma unroll
    for (int off = F / 2; off > 0; off >>= 1) m = fmaxf(m, __shfl_xor(m, off, F));

    // pass 2: exp -> stash, running sum
    float selfw = __expf(selft - m);
    float l = (lane == 0) ? selfw : 0.f;
#pragma unroll
    for (int k = 0; k < K; ++k) {
        int j = k * F + lane;
        if (j < deg) {
            float e = __expf(wreg[k] - m);
            wreg[k] = e;
            l += e;
        }
    }
    for (int j = K * F + lane; j < deg; j += F)
        l += __expf(llrelu(Ssrc[esrc[rs + j]] + sdi) - m);
#pragma unroll
    for (int off = F / 2; off > 0; off >>= 1) l += __shfl_xor(l, off, F);
    float winv = 1.f / l;

    // pass 3: acc = sum_j w_j * H[s_j][lane], 8 gathers in flight per batch
    float acc = selfw * H[(size_t)node * F + lane];
#pragma unroll
    for (int k = 0; k < K; ++k) {
        int j0 = k * F;
        if (j0 < deg) {
            int cnt = min(F, deg - j0);
            float wme = wreg[k];
            int sme = sreg[k];
            for (int jj = 0; jj < cnt; jj += 8) {
                float wv[8];
                int sv[8];
                float hv[8];
#pragma unroll
                for (int u = 0; u < 8; ++u) {
                    bool ok = (jj + u) < cnt;     // group-uniform predicate
                    int ln = ok ? (jj + u) : jj;  // clamp -> same-address L1 hit
                    wv[u] = ok ? __shfl(wme, ln, F) : 0.f;
                    sv[u] = __shfl(sme, ln, F);
                }
#pragma unroll
                for (int u = 0; u < 8; ++u) hv[u] = H[(size_t)sv[u] * F + lane];
#pragma unroll
                for (int u = 0; u < 8; ++u) acc = fmaf(wv[u], hv[u], acc);
            }
        }
    }
    for (int j = K * F; j < deg; ++j) {  // overflow: all lanes recompute w_j
        int s = esrc[rs + j];
        float wj = __expf(llrelu(Ssrc[s] + sdi) - m);
        acc = fmaf(wj, H[(size_t)s * F + lane], acc);
    }

    acc *= winv;
    if (WITH_BIAS) acc += bias[lane];
    OUT[(size_t)node * F + lane] = acc;
}

// Sum OUT3 over nodes into facc[32].
__global__ void mean_kernel(const float* __restrict__ B, float* __restrict__ facc, int n) {
    __shared__ float s[32];
    int lane = threadIdx.x & 31, row = threadIdx.x >> 5;
    float a = 0.f;
    for (int node = blockIdx.x * 8 + row; node < n; node += gridDim.x * 8)
        a += B[(size_t)node * 32 + lane];
    if (threadIdx.x < 32) s[threadIdx.x] = 0.f;
    __syncthreads();
    atomicAdd(&s[lane], a);
    __syncthreads();
    if (threadIdx.x < 32) atomicAdd(&facc[threadIdx.x], s[threadIdx.x]);
}

__global__ void finalize_kernel(const float* __restrict__ facc, const float* __restrict__ b,
                                const float* __restrict__ tdp, const float* __restrict__ cansup,
                                float* __restrict__ out, int n) {
    int f = threadIdx.x;
    if (f < 32) {
        float td = tdp[0] * cansup[0];
        out[f] = (facc[f] / (float)n + b[f]) * td;
    }
}

extern "C" void kernel_launch(void* const* d_in, const int* in_sizes, int n_in,
                              void* d_out, int out_size, void* d_ws, size_t ws_size,
                              hipStream_t stream) {
    const float* x      = (const float*)d_in[0];
    const int* eidx     = (const int*)d_in[1];
    const float* W1     = (const float*)d_in[2];
    const float* as1    = (const float*)d_in[3];
    const float* ad1    = (const float*)d_in[4];
    const float* b1     = (const float*)d_in[5];
    const float* W2     = (const float*)d_in[6];
    const float* as2    = (const float*)d_in[7];
    const float* ad2    = (const float*)d_in[8];
    const float* b2     = (const float*)d_in[9];
    const float* W3     = (const float*)d_in[10];
    const float* as3    = (const float*)d_in[11];
    const float* ad3    = (const float*)d_in[12];
    const float* b3     = (const float*)d_in[13];
    const float* tdp    = (const float*)d_in[14];
    const float* cansup = (const float*)d_in[15];

    const int n = in_sizes[0] / 64;   // 100000 nodes
    const int E = in_sizes[1] / 2;    // 1600000 edges
    const int* srcp = eidx;
    const int* dstp = eidx + E;

    char* ws = (char*)d_ws;
    size_t off = 0;
    auto alloc = [&](size_t bytes) -> void* {
        void* p = ws + off;
        off += (bytes + 255) & ~(size_t)255;
        return p;
    };
    float* A      = (float*)alloc((size_t)n * 64 * sizeof(float));  // H
    float* B      = (float*)alloc((size_t)n * 64 * sizeof(float));  // layer out
    float* ssrc   = (float*)alloc((size_t)n * sizeof(float));
    float* sdst   = (float*)alloc((size_t)n * sizeof(float));
    int*   counts = (int*)alloc((size_t)n * sizeof(int));
    int*   rowst  = (int*)alloc((size_t)(n + 1) * sizeof(int));
    int*   bsums  = (int*)alloc(1024 * sizeof(int));
    int*   esrc   = (int*)alloc((size_t)E * sizeof(int));
    int*   rank   = (int*)alloc((size_t)E * sizeof(int));
    float* facc   = (float*)alloc(64 * sizeof(float));

    // ---- CSR build (once; graph shared across layers) ----
    zero_int_kernel<<<(n + 255) / 256, 256, 0, stream>>>(counts, n);
    zero_float_kernel<<<1, 64, 0, stream>>>(facc, 32);
    count_rank_kernel<<<2048, 256, 0, stream>>>(dstp, E, counts, rank);
    int nb = (n + 1023) / 1024;
    scan_phase1<<<nb, 1024, 0, stream>>>(counts, n, rowst, bsums);
    scan_phase2<<<1, 1024, 0, stream>>>(bsums, nb);
    scan_phase3<<<(n + 255) / 256, 256, 0, stream>>>(rowst, bsums, n, E);
    fill_kernel<<<2048, 256, 0, stream>>>(srcp, dstp, rank, E, rowst, esrc);

    // ---- layer 1: 64 -> 64 (ReLU folded into layer-2 gemm load) ----
    gemm_att_kernel<64, 64, false><<<(n + 3) / 4, BLOCK, 0, stream>>>(x, W1, as1, ad1, A, ssrc, sdst, n);
    gat_aggr_kernel<64, 2, true><<<(n + 3) / 4, BLOCK, 0, stream>>>(A, ssrc, sdst, rowst, esrc, b1, B, n);

    // ---- layer 2: 64 -> 32 (ReLU folded into layer-3 gemm load) ----
    gemm_att_kernel<64, 32, true><<<(n + 7) / 8, BLOCK, 0, stream>>>(B, W2, as2, ad2, A, ssrc, sdst, n);
    gat_aggr_kernel<32, 4, true><<<(n + 7) / 8, BLOCK, 0, stream>>>(A, ssrc, sdst, rowst, esrc, b2, B, n);

    // ---- layer 3: 32 -> 32, then global mean ----
    gemm_att_kernel<32, 32, true><<<(n + 7) / 8, BLOCK, 0, stream>>>(B, W3, as3, ad3, A, ssrc, sdst, n);
    gat_aggr_kernel<32, 4, false><<<(n + 7) / 8, BLOCK, 0, stream>>>(A, ssrc, sdst, rowst, esrc, nullptr, B, n);
    mean_kernel<<<1024, 256, 0, stream>>>(B, facc, n);
    finalize_kernel<<<1, 64, 0, stream>>>(facc, b3, tdp, cansup, (float*)d_out, n);
}

// Round 3
// 384.968 us; speedup vs baseline: 1.3753x; 1.0525x over previous
//
#include <hip/hip_runtime.h>

// 3-layer GAT (PyG GATConv) on MI355X.
// CSR build: count_rank (atomicAdd returns in-bucket rank) -> scan -> fill
// (pure scatter, no atomics, esrc only; edst never materialized).
// Per layer: gemm_att (register-resident W column per lane, zero LDS in the
// K loop; broadcast float4 X loads; fused attention dots) -> gat_aggr
// (node-parallel fused softmax + gather-FMA, 8-deep gather MLP).

constexpr int BLOCK = 256;

__device__ __forceinline__ float llrelu(float x) { return x >= 0.f ? x : 0.2f * x; }

__global__ void zero_int_kernel(int* __restrict__ p, int count) {
    int i = blockIdx.x * blockDim.x + threadIdx.x;
    int stride = gridDim.x * blockDim.x;
    for (; i < count; i += stride) p[i] = 0;
}

__global__ void zero_float_kernel(float* __restrict__ p, int count) {
    int i = blockIdx.x * blockDim.x + threadIdx.x;
    if (i < count) p[i] = 0.f;
}

// counts[d]++ per edge; the atomic's return value IS the edge's rank within
// its dst bucket (arrival order; any stable-enough order is valid for CSR).
__global__ void count_rank_kernel(const int* __restrict__ dst, int E,
                                  int* __restrict__ counts, int* __restrict__ rank) {
    int i = blockIdx.x * blockDim.x + threadIdx.x;
    int stride = gridDim.x * blockDim.x;
    for (; i < E; i += stride) rank[i] = atomicAdd(&counts[dst[i]], 1);
}

__global__ void scan_phase1(const int* __restrict__ counts, int n,
                            int* __restrict__ excl, int* __restrict__ block_sums) {
    __shared__ int s[1024];
    int tid = threadIdx.x;
    int gid = blockIdx.x * 1024 + tid;
    int v = (gid < n) ? counts[gid] : 0;
    s[tid] = v;
    for (int off = 1; off < 1024; off <<= 1) {
        __syncthreads();
        int t = (tid >= off) ? s[tid - off] : 0;
        __syncthreads();
        s[tid] += t;
    }
    __syncthreads();
    if (gid < n) excl[gid] = s[tid] - v;
    if (tid == 1023) block_sums[blockIdx.x] = s[tid];
}

__global__ void scan_phase2(int* __restrict__ block_sums, int nb) {
    __shared__ int s[1024];
    int tid = threadIdx.x;
    int v = (tid < nb) ? block_sums[tid] : 0;
    s[tid] = v;
    for (int off = 1; off < 1024; off <<= 1) {
        __syncthreads();
        int t = (tid >= off) ? s[tid - off] : 0;
        __syncthreads();
        s[tid] += t;
    }
    __syncthreads();
    if (tid < nb) block_sums[tid] = s[tid] - v;  // exclusive
}

__global__ void scan_phase3(int* __restrict__ row_start, const int* __restrict__ block_sums,
                            int n, int E) {
    int gid = blockIdx.x * blockDim.x + threadIdx.x;
    if (gid < n) row_start[gid] += block_sums[gid >> 10];
    if (gid == 0) row_start[n] = E;
}

// Pure scatter: slot = row_start[dst] + rank. No atomics, single 4B payload.
__global__ void fill_kernel(const int* __restrict__ src, const int* __restrict__ dst,
                            const int* __restrict__ rank, int E,
                            const int* __restrict__ row_start, int* __restrict__ esrc) {
    int i = blockIdx.x * blockDim.x + threadIdx.x;
    int stride = gridDim.x * blockDim.x;
    for (; i < E; i += stride) esrc[row_start[dst[i]] + rank[i]] = src[i];
}

// H = relu?(X) @ W, plus fused attention dots Ssrc = H.a_src, Sdst = H.a_dst.
// Each lane owns one W column in registers (compile-time indexed => VGPRs);
// K loop is pure FMA, no LDS. Grid-strided so the one-time W load amortizes
// over ~25 nodes per group (W re-reads are L2-resident).
template <int FIN, int FOUT, bool RELU_IN>
__global__ void gemm_att_kernel(const float* __restrict__ X, const float* __restrict__ W,
                                const float* __restrict__ asrc, const float* __restrict__ adst,
                                float* __restrict__ H, float* __restrict__ Ssrc,
                                float* __restrict__ Sdst, int n) {
    constexpr int GPB = BLOCK / FOUT;  // node-slots per block
    int tid = threadIdx.x;
    int col = tid % FOUT;
    int grp = tid / FOUT;

    float wreg[FIN];
#pragma unroll
    for (int k = 0; k < FIN; ++k) wreg[k] = W[k * FOUT + col];
    float as = asrc[col], ad = adst[col];

    int stride = gridDim.x * GPB;
    for (int node = blockIdx.x * GPB + grp; node < n; node += stride) {
        const float4* xr4 = (const float4*)(X + (size_t)node * FIN);
        float acc0 = 0.f, acc1 = 0.f, acc2 = 0.f, acc3 = 0.f;
#pragma unroll
        for (int c = 0; c < FIN / 32; ++c) {
            float4 xv[8];
#pragma unroll
            for (int j = 0; j < 8; ++j) xv[j] = xr4[c * 8 + j];
#pragma unroll
            for (int j = 0; j < 8; ++j) {
                float4 v = xv[j];
                if (RELU_IN) {
                    v.x = fmaxf(v.x, 0.f); v.y = fmaxf(v.y, 0.f);
                    v.z = fmaxf(v.z, 0.f); v.w = fmaxf(v.w, 0.f);
                }
                int k = c * 32 + j * 4;
                acc0 = fmaf(v.x, wreg[k + 0], acc0);
                acc1 = fmaf(v.y, wreg[k + 1], acc1);
                acc2 = fmaf(v.z, wreg[k + 2], acc2);
                acc3 = fmaf(v.w, wreg[k + 3], acc3);
            }
        }
        float acc = (acc0 + acc1) + (acc2 + acc3);
        H[(size_t)node * FOUT + col] = acc;

        float vs = acc * as;
        float vd = acc * ad;
#pragma unroll
        for (int off = FOUT / 2; off > 0; off >>= 1) {
            vs += __shfl_xor(vs, off, FOUT);
            vd += __shfl_xor(vd, off, FOUT);
        }
        if (col == 0) {
            Ssrc[node] = vs;
            Sdst[node] = vd;
        }
    }
}

// Node-parallel fused softmax + aggregation. One F-lane group per node:
// pass1 logits (register stash, K slots/lane => deg<=K*F fast path),
// pass2 exp+sum, pass3 shuffle-broadcast weighted gather-FMA over H rows,
// batched 8-deep so 8 row-gathers are in flight per wave (latency hiding).
// Tail slots clamp to the batch's first slot with weight 0: same-address
// L1-hit load, group-uniform predicate (no divergence, no wasted HBM).
// Overflow rows (deg > K*F) take a correct recompute path.
template <int F, int K, bool WITH_BIAS>
__global__ void gat_aggr_kernel(const float* __restrict__ H, const float* __restrict__ Ssrc,
                                const float* __restrict__ Sdst, const int* __restrict__ row_start,
                                const int* __restrict__ esrc, const float* __restrict__ bias,
                                float* __restrict__ OUT, int n) {
    int tid = threadIdx.x;
    int node = blockIdx.x * (BLOCK / F) + tid / F;
    int lane = tid % F;
    if (node >= n) return;

    int rs = row_start[node];
    int deg = row_start[node + 1] - rs;
    float sdi = Sdst[node];
    float selft = llrelu(Ssrc[node] + sdi);

    int sreg[K];
    float wreg[K];

    // pass 1: logits -> stash, running max (self-loop included, PyG semantics)
    float m = selft;
#pragma unroll
    for (int k = 0; k < K; ++k) {
        int j = k * F + lane;
        if (j < deg) {
            int s = esrc[rs + j];
            float t = llrelu(Ssrc[s] + sdi);
            sreg[k] = s;
            wreg[k] = t;
            m = fmaxf(m, t);
        }
    }
    for (int j = K * F + lane; j < deg; j += F)  // overflow (deg > K*F): rare
        m = fmaxf(m, llrelu(Ssrc[esrc[rs + j]] + sdi));
#pragma unroll
    for (int off = F / 2; off > 0; off >>= 1) m = fmaxf(m, __shfl_xor(m, off, F));

    // pass 2: exp -> stash, running sum
    float selfw = __expf(selft - m);
    float l = (lane == 0) ? selfw : 0.f;
#pragma unroll
    for (int k = 0; k < K; ++k) {
        int j = k * F + lane;
        if (j < deg) {
            float e = __expf(wreg[k] - m);
            wreg[k] = e;
            l += e;
        }
    }
    for (int j = K * F + lane; j < deg; j += F)
        l += __expf(llrelu(Ssrc[esrc[rs + j]] + sdi) - m);
#pragma unroll
    for (int off = F / 2; off > 0; off >>= 1) l += __shfl_xor(l, off, F);
    float winv = 1.f / l;

    // pass 3: acc = sum_j w_j * H[s_j][lane], 8 gathers in flight per batch
    float acc = selfw * H[(size_t)node * F + lane];
#pragma unroll
    for (int k = 0; k < K; ++k) {
        int j0 = k * F;
        if (j0 < deg) {
            int cnt = min(F, deg - j0);
            float wme = wreg[k];
            int sme = sreg[k];
            for (int jj = 0; jj < cnt; jj += 8) {
                float wv[8];
                int sv[8];
                float hv[8];
#pragma unroll
                for (int u = 0; u < 8; ++u) {
                    bool ok = (jj + u) < cnt;     // group-uniform predicate
                    int ln = ok ? (jj + u) : jj;  // clamp -> same-address L1 hit
                    wv[u] = ok ? __shfl(wme, ln, F) : 0.f;
                    sv[u] = __shfl(sme, ln, F);
                }
#pragma unroll
                for (int u = 0; u < 8; ++u) hv[u] = H[(size_t)sv[u] * F + lane];
#pragma unroll
                for (int u = 0; u < 8; ++u) acc = fmaf(wv[u], hv[u], acc);
            }
        }
    }
    for (int j = K * F; j < deg; ++j) {  // overflow: all lanes recompute w_j
        int s = esrc[rs + j];
        float wj = __expf(llrelu(Ssrc[s] + sdi) - m);
        acc = fmaf(wj, H[(size_t)s * F + lane], acc);
    }

    acc *= winv;
    if (WITH_BIAS) acc += bias[lane];
    OUT[(size_t)node * F + lane] = acc;
}

// Sum OUT3 over nodes into facc[32].
__global__ void mean_kernel(const float* __restrict__ B, float* __restrict__ facc, int n) {
    __shared__ float s[32];
    int lane = threadIdx.x & 31, row = threadIdx.x >> 5;
    float a = 0.f;
    for (int node = blockIdx.x * 8 + row; node < n; node += gridDim.x * 8)
        a += B[(size_t)node * 32 + lane];
    if (threadIdx.x < 32) s[threadIdx.x] = 0.f;
    __syncthreads();
    atomicAdd(&s[lane], a);
    __syncthreads();
    if (threadIdx.x < 32) atomicAdd(&facc[threadIdx.x], s[threadIdx.x]);
}

__global__ void finalize_kernel(const float* __restrict__ facc, const float* __restrict__ b,
                                const float* __restrict__ tdp, const float* __restrict__ cansup,
                                float* __restrict__ out, int n) {
    int f = threadIdx.x;
    if (f < 32) {
        float td = tdp[0] * cansup[0];
        out[f] = (facc[f] / (float)n + b[f]) * td;
    }
}

extern "C" void kernel_launch(void* const* d_in, const int* in_sizes, int n_in,
                              void* d_out, int out_size, void* d_ws, size_t ws_size,
                              hipStream_t stream) {
    const float* x      = (const float*)d_in[0];
    const int* eidx     = (const int*)d_in[1];
    const float* W1     = (const float*)d_in[2];
    const float* as1    = (const float*)d_in[3];
    const float* ad1    = (const float*)d_in[4];
    const float* b1     = (const float*)d_in[5];
    const float* W2     = (const float*)d_in[6];
    const float* as2    = (const float*)d_in[7];
    const float* ad2    = (const float*)d_in[8];
    const float* b2     = (const float*)d_in[9];
    const float* W3     = (const float*)d_in[10];
    const float* as3    = (const float*)d_in[11];
    const float* ad3    = (const float*)d_in[12];
    const float* b3     = (const float*)d_in[13];
    const float* tdp    = (const float*)d_in[14];
    const float* cansup = (const float*)d_in[15];

    const int n = in_sizes[0] / 64;   // 100000 nodes
    const int E = in_sizes[1] / 2;    // 1600000 edges
    const int* srcp = eidx;
    const int* dstp = eidx + E;

    char* ws = (char*)d_ws;
    size_t off = 0;
    auto alloc = [&](size_t bytes) -> void* {
        void* p = ws + off;
        off += (bytes + 255) & ~(size_t)255;
        return p;
    };
    float* A      = (float*)alloc((size_t)n * 64 * sizeof(float));  // H
    float* B      = (float*)alloc((size_t)n * 64 * sizeof(float));  // layer out
    float* ssrc   = (float*)alloc((size_t)n * sizeof(float));
    float* sdst   = (float*)alloc((size_t)n * sizeof(float));
    int*   counts = (int*)alloc((size_t)n * sizeof(int));
    int*   rowst  = (int*)alloc((size_t)(n + 1) * sizeof(int));
    int*   bsums  = (int*)alloc(1024 * sizeof(int));
    int*   esrc   = (int*)alloc((size_t)E * sizeof(int));
    int*   rank   = (int*)alloc((size_t)E * sizeof(int));
    float* facc   = (float*)alloc(64 * sizeof(float));

    // ---- CSR build (once; graph shared across layers) ----
    zero_int_kernel<<<(n + 255) / 256, 256, 0, stream>>>(counts, n);
    zero_float_kernel<<<1, 64, 0, stream>>>(facc, 32);
    count_rank_kernel<<<2048, 256, 0, stream>>>(dstp, E, counts, rank);
    int nb = (n + 1023) / 1024;
    scan_phase1<<<nb, 1024, 0, stream>>>(counts, n, rowst, bsums);
    scan_phase2<<<1, 1024, 0, stream>>>(bsums, nb);
    scan_phase3<<<(n + 255) / 256, 256, 0, stream>>>(rowst, bsums, n, E);
    fill_kernel<<<2048, 256, 0, stream>>>(srcp, dstp, rank, E, rowst, esrc);

    // ---- layer 1: 64 -> 64 (ReLU folded into layer-2 gemm load) ----
    gemm_att_kernel<64, 64, false><<<1024, BLOCK, 0, stream>>>(x, W1, as1, ad1, A, ssrc, sdst, n);
    gat_aggr_kernel<64, 2, true><<<(n + 3) / 4, BLOCK, 0, stream>>>(A, ssrc, sdst, rowst, esrc, b1, B, n);

    // ---- layer 2: 64 -> 32 (ReLU folded into layer-3 gemm load) ----
    gemm_att_kernel<64, 32, true><<<1024, BLOCK, 0, stream>>>(B, W2, as2, ad2, A, ssrc, sdst, n);
    gat_aggr_kernel<32, 4, true><<<(n + 7) / 8, BLOCK, 0, stream>>>(A, ssrc, sdst, rowst, esrc, b2, B, n);

    // ---- layer 3: 32 -> 32, then global mean ----
    gemm_att_kernel<32, 32, true><<<1024, BLOCK, 0, stream>>>(B, W3, as3, ad3, A, ssrc, sdst, n);
    gat_aggr_kernel<32, 4, false><<<(n + 7) / 8, BLOCK, 0, stream>>>(A, ssrc, sdst, rowst, esrc, nullptr, B, n);
    mean_kernel<<<1024, 256, 0, stream>>>(B, facc, n);
    finalize_kernel<<<1, 64, 0, stream>>>(facc, b3, tdp, cansup, (float*)d_out, n);
}

// Round 4
// 322.773 us; speedup vs baseline: 1.6403x; 1.1927x over previous
//
#include <hip/hip_runtime.h>

// 3-layer GAT (PyG GATConv) on MI355X.
// CSR build: count_rank (atomicAdd returns in-bucket rank) -> scan -> fill
// (pure scatter, no atomics, esrc only; edst never materialized).
// Per layer: gemm_att (micro-tiled LDS GEMM: 4 nodes x 4 cols register tile
// per thread, ds_read_b128 operand loads, fused attention dots) -> gat_aggr
// (node-parallel fused softmax + gather-FMA, 8-deep gather MLP).

constexpr int BLOCK = 256;

__device__ __forceinline__ float llrelu(float x) { return x >= 0.f ? x : 0.2f * x; }

__global__ void zero_int_kernel(int* __restrict__ p, int count) {
    int i = blockIdx.x * blockDim.x + threadIdx.x;
    int stride = gridDim.x * blockDim.x;
    for (; i < count; i += stride) p[i] = 0;
}

__global__ void zero_float_kernel(float* __restrict__ p, int count) {
    int i = blockIdx.x * blockDim.x + threadIdx.x;
    if (i < count) p[i] = 0.f;
}

// counts[d]++ per edge; the atomic's return value IS the edge's rank within
// its dst bucket (arrival order; any stable-enough order is valid for CSR).
__global__ void count_rank_kernel(const int* __restrict__ dst, int E,
                                  int* __restrict__ counts, int* __restrict__ rank) {
    int i = blockIdx.x * blockDim.x + threadIdx.x;
    int stride = gridDim.x * blockDim.x;
    for (; i < E; i += stride) rank[i] = atomicAdd(&counts[dst[i]], 1);
}

__global__ void scan_phase1(const int* __restrict__ counts, int n,
                            int* __restrict__ excl, int* __restrict__ block_sums) {
    __shared__ int s[1024];
    int tid = threadIdx.x;
    int gid = blockIdx.x * 1024 + tid;
    int v = (gid < n) ? counts[gid] : 0;
    s[tid] = v;
    for (int off = 1; off < 1024; off <<= 1) {
        __syncthreads();
        int t = (tid >= off) ? s[tid - off] : 0;
        __syncthreads();
        s[tid] += t;
    }
    __syncthreads();
    if (gid < n) excl[gid] = s[tid] - v;
    if (tid == 1023) block_sums[blockIdx.x] = s[tid];
}

__global__ void scan_phase2(int* __restrict__ block_sums, int nb) {
    __shared__ int s[1024];
    int tid = threadIdx.x;
    int v = (tid < nb) ? block_sums[tid] : 0;
    s[tid] = v;
    for (int off = 1; off < 1024; off <<= 1) {
        __syncthreads();
        int t = (tid >= off) ? s[tid - off] : 0;
        __syncthreads();
        s[tid] += t;
    }
    __syncthreads();
    if (tid < nb) block_sums[tid] = s[tid] - v;  // exclusive
}

__global__ void scan_phase3(int* __restrict__ row_start, const int* __restrict__ block_sums,
                            int n, int E) {
    int gid = blockIdx.x * blockDim.x + threadIdx.x;
    if (gid < n) row_start[gid] += block_sums[gid >> 10];
    if (gid == 0) row_start[n] = E;
}

// Pure scatter: slot = row_start[dst] + rank. No atomics, single 4B payload.
__global__ void fill_kernel(const int* __restrict__ src, const int* __restrict__ dst,
                            const int* __restrict__ rank, int E,
                            const int* __restrict__ row_start, int* __restrict__ esrc) {
    int i = blockIdx.x * blockDim.x + threadIdx.x;
    int stride = gridDim.x * blockDim.x;
    for (; i < E; i += stride) esrc[row_start[dst[i]] + rank[i]] = src[i];
}

// H = relu?(X) @ W, plus fused attention dots Ssrc = H.a_src, Sdst = H.a_dst.
// Micro-tiled: each thread owns a 4-node x 4-col register tile; X tile and W
// staged in LDS once per block, read via ds_read_b128. X rows padded to
// FIN+4 floats (16B-aligned, spreads the 4-row broadcast across bank groups).
template <int FIN, int FOUT, bool RELU_IN>
__global__ void gemm_att_kernel(const float* __restrict__ X, const float* __restrict__ W,
                                const float* __restrict__ asrc, const float* __restrict__ adst,
                                float* __restrict__ H, float* __restrict__ Ssrc,
                                float* __restrict__ Sdst, int n) {
    constexpr int CG = FOUT / 4;    // column groups (threads per node-row set)
    constexpr int NG = BLOCK / CG;  // node groups
    constexpr int TN = NG * 4;      // nodes per block
    constexpr int S = FIN + 4;      // padded LDS row stride (floats)
    __shared__ float Xs[TN * S];
    __shared__ float Ws[FIN * FOUT];

    int tid = threadIdx.x;
    int n0_blk = blockIdx.x * TN;

    // stage W (unpadded row-major, matches global layout)
    for (int t = tid; t < FIN * FOUT / 4; t += BLOCK) {
        float4 v = ((const float4*)W)[t];
        *(float4*)&Ws[t * 4] = v;
    }
    // stage X tile (clamp out-of-range rows to keep addresses valid)
    constexpr int RW = FIN / 4;  // float4 per row
    for (int t = tid; t < TN * RW; t += BLOCK) {
        int r = t / RW, c = t % RW;
        int gr = n0_blk + r;
        if (gr >= n) gr = n - 1;
        float4 v = ((const float4*)(X + (size_t)gr * FIN))[c];
        if (RELU_IN) {
            v.x = fmaxf(v.x, 0.f); v.y = fmaxf(v.y, 0.f);
            v.z = fmaxf(v.z, 0.f); v.w = fmaxf(v.w, 0.f);
        }
        *(float4*)&Xs[r * S + c * 4] = v;
    }
    __syncthreads();

    int tx = tid % CG;       // column group
    int ty = tid / CG;       // node group
    int c0 = tx * 4;
    int nloc = ty * 4;

    float acc[4][4];
#pragma unroll
    for (int i = 0; i < 4; ++i)
#pragma unroll
        for (int j = 0; j < 4; ++j) acc[i][j] = 0.f;

#pragma unroll 2
    for (int kc = 0; kc < FIN / 4; ++kc) {
        float4 xv[4], wv[4];
#pragma unroll
        for (int i = 0; i < 4; ++i) xv[i] = *(const float4*)&Xs[(nloc + i) * S + kc * 4];
#pragma unroll
        for (int kk = 0; kk < 4; ++kk) wv[kk] = *(const float4*)&Ws[(kc * 4 + kk) * FOUT + c0];
#pragma unroll
        for (int i = 0; i < 4; ++i) {
            float xi0 = xv[i].x, xi1 = xv[i].y, xi2 = xv[i].z, xi3 = xv[i].w;
            acc[i][0] = fmaf(xi0, wv[0].x, acc[i][0]);
            acc[i][1] = fmaf(xi0, wv[0].y, acc[i][1]);
            acc[i][2] = fmaf(xi0, wv[0].z, acc[i][2]);
            acc[i][3] = fmaf(xi0, wv[0].w, acc[i][3]);
            acc[i][0] = fmaf(xi1, wv[1].x, acc[i][0]);
            acc[i][1] = fmaf(xi1, wv[1].y, acc[i][1]);
            acc[i][2] = fmaf(xi1, wv[1].z, acc[i][2]);
            acc[i][3] = fmaf(xi1, wv[1].w, acc[i][3]);
            acc[i][0] = fmaf(xi2, wv[2].x, acc[i][0]);
            acc[i][1] = fmaf(xi2, wv[2].y, acc[i][1]);
            acc[i][2] = fmaf(xi2, wv[2].z, acc[i][2]);
            acc[i][3] = fmaf(xi2, wv[2].w, acc[i][3]);
            acc[i][0] = fmaf(xi3, wv[3].x, acc[i][0]);
            acc[i][1] = fmaf(xi3, wv[3].y, acc[i][1]);
            acc[i][2] = fmaf(xi3, wv[3].z, acc[i][2]);
            acc[i][3] = fmaf(xi3, wv[3].w, acc[i][3]);
        }
    }

    float4 as4 = *(const float4*)&asrc[c0];
    float4 ad4 = *(const float4*)&adst[c0];

#pragma unroll
    for (int i = 0; i < 4; ++i) {
        int node = n0_blk + nloc + i;
        bool ok = node < n;
        if (ok) {
            float4 hv = make_float4(acc[i][0], acc[i][1], acc[i][2], acc[i][3]);
            *(float4*)&H[(size_t)node * FOUT + c0] = hv;
        }
        float vs = acc[i][0] * as4.x + acc[i][1] * as4.y + acc[i][2] * as4.z + acc[i][3] * as4.w;
        float vd = acc[i][0] * ad4.x + acc[i][1] * ad4.y + acc[i][2] * ad4.z + acc[i][3] * ad4.w;
#pragma unroll
        for (int off = CG / 2; off > 0; off >>= 1) {
            vs += __shfl_xor(vs, off, CG);
            vd += __shfl_xor(vd, off, CG);
        }
        if (tx == 0 && ok) {
            Ssrc[node] = vs;
            Sdst[node] = vd;
        }
    }
}

// Node-parallel fused softmax + aggregation. One F-lane group per node:
// pass1 logits (register stash, K slots/lane => deg<=K*F fast path),
// pass2 exp+sum, pass3 shuffle-broadcast weighted gather-FMA over H rows,
// batched 8-deep so 8 row-gathers are in flight per wave (latency hiding).
// Tail slots clamp to the batch's first slot with weight 0: same-address
// L1-hit load, group-uniform predicate (no divergence, no wasted HBM).
// Overflow rows (deg > K*F) take a correct recompute path.
template <int F, int K, bool WITH_BIAS>
__global__ void gat_aggr_kernel(const float* __restrict__ H, const float* __restrict__ Ssrc,
                                const float* __restrict__ Sdst, const int* __restrict__ row_start,
                                const int* __restrict__ esrc, const float* __restrict__ bias,
                                float* __restrict__ OUT, int n) {
    int tid = threadIdx.x;
    int node = blockIdx.x * (BLOCK / F) + tid / F;
    int lane = tid % F;
    if (node >= n) return;

    int rs = row_start[node];
    int deg = row_start[node + 1] - rs;
    float sdi = Sdst[node];
    float selft = llrelu(Ssrc[node] + sdi);

    int sreg[K];
    float wreg[K];

    // pass 1: logits -> stash, running max (self-loop included, PyG semantics)
    float m = selft;
#pragma unroll
    for (int k = 0; k < K; ++k) {
        int j = k * F + lane;
        if (j < deg) {
            int s = esrc[rs + j];
            float t = llrelu(Ssrc[s] + sdi);
            sreg[k] = s;
            wreg[k] = t;
            m = fmaxf(m, t);
        }
    }
    for (int j = K * F + lane; j < deg; j += F)  // overflow (deg > K*F): rare
        m = fmaxf(m, llrelu(Ssrc[esrc[rs + j]] + sdi));
#pragma unroll
    for (int off = F / 2; off > 0; off >>= 1) m = fmaxf(m, __shfl_xor(m, off, F));

    // pass 2: exp -> stash, running sum
    float selfw = __expf(selft - m);
    float l = (lane == 0) ? selfw : 0.f;
#pragma unroll
    for (int k = 0; k < K; ++k) {
        int j = k * F + lane;
        if (j < deg) {
            float e = __expf(wreg[k] - m);
            wreg[k] = e;
            l += e;
        }
    }
    for (int j = K * F + lane; j < deg; j += F)
        l += __expf(llrelu(Ssrc[esrc[rs + j]] + sdi) - m);
#pragma unroll
    for (int off = F / 2; off > 0; off >>= 1) l += __shfl_xor(l, off, F);
    float winv = 1.f / l;

    // pass 3: acc = sum_j w_j * H[s_j][lane], 8 gathers in flight per batch
    float acc = selfw * H[(size_t)node * F + lane];
#pragma unroll
    for (int k = 0; k < K; ++k) {
        int j0 = k * F;
        if (j0 < deg) {
            int cnt = min(F, deg - j0);
            float wme = wreg[k];
            int sme = sreg[k];
            for (int jj = 0; jj < cnt; jj += 8) {
                float wv[8];
                int sv[8];
                float hv[8];
#pragma unroll
                for (int u = 0; u < 8; ++u) {
                    bool ok = (jj + u) < cnt;     // group-uniform predicate
                    int ln = ok ? (jj + u) : jj;  // clamp -> same-address L1 hit
                    wv[u] = ok ? __shfl(wme, ln, F) : 0.f;
                    sv[u] = __shfl(sme, ln, F);
                }
#pragma unroll
                for (int u = 0; u < 8; ++u) hv[u] = H[(size_t)sv[u] * F + lane];
#pragma unroll
                for (int u = 0; u < 8; ++u) acc = fmaf(wv[u], hv[u], acc);
            }
        }
    }
    for (int j = K * F; j < deg; ++j) {  // overflow: all lanes recompute w_j
        int s = esrc[rs + j];
        float wj = __expf(llrelu(Ssrc[s] + sdi) - m);
        acc = fmaf(wj, H[(size_t)s * F + lane], acc);
    }

    acc *= winv;
    if (WITH_BIAS) acc += bias[lane];
    OUT[(size_t)node * F + lane] = acc;
}

// Sum OUT3 over nodes into facc[32].
__global__ void mean_kernel(const float* __restrict__ B, float* __restrict__ facc, int n) {
    __shared__ float s[32];
    int lane = threadIdx.x & 31, row = threadIdx.x >> 5;
    float a = 0.f;
    for (int node = blockIdx.x * 8 + row; node < n; node += gridDim.x * 8)
        a += B[(size_t)node * 32 + lane];
    if (threadIdx.x < 32) s[threadIdx.x] = 0.f;
    __syncthreads();
    atomicAdd(&s[lane], a);
    __syncthreads();
    if (threadIdx.x < 32) atomicAdd(&facc[threadIdx.x], s[threadIdx.x]);
}

__global__ void finalize_kernel(const float* __restrict__ facc, const float* __restrict__ b,
                                const float* __restrict__ tdp, const float* __restrict__ cansup,
                                float* __restrict__ out, int n) {
    int f = threadIdx.x;
    if (f < 32) {
        float td = tdp[0] * cansup[0];
        out[f] = (facc[f] / (float)n + b[f]) * td;
    }
}

extern "C" void kernel_launch(void* const* d_in, const int* in_sizes, int n_in,
                              void* d_out, int out_size, void* d_ws, size_t ws_size,
                              hipStream_t stream) {
    const float* x      = (const float*)d_in[0];
    const int* eidx     = (const int*)d_in[1];
    const float* W1     = (const float*)d_in[2];
    const float* as1    = (const float*)d_in[3];
    const float* ad1    = (const float*)d_in[4];
    const float* b1     = (const float*)d_in[5];
    const float* W2     = (const float*)d_in[6];
    const float* as2    = (const float*)d_in[7];
    const float* ad2    = (const float*)d_in[8];
    const float* b2     = (const float*)d_in[9];
    const float* W3     = (const float*)d_in[10];
    const float* as3    = (const float*)d_in[11];
    const float* ad3    = (const float*)d_in[12];
    const float* b3     = (const float*)d_in[13];
    const float* tdp    = (const float*)d_in[14];
    const float* cansup = (const float*)d_in[15];

    const int n = in_sizes[0] / 64;   // 100000 nodes
    const int E = in_sizes[1] / 2;    // 1600000 edges
    const int* srcp = eidx;
    const int* dstp = eidx + E;

    char* ws = (char*)d_ws;
    size_t off = 0;
    auto alloc = [&](size_t bytes) -> void* {
        void* p = ws + off;
        off += (bytes + 255) & ~(size_t)255;
        return p;
    };
    float* A      = (float*)alloc((size_t)n * 64 * sizeof(float));  // H
    float* B      = (float*)alloc((size_t)n * 64 * sizeof(float));  // layer out
    float* ssrc   = (float*)alloc((size_t)n * sizeof(float));
    float* sdst   = (float*)alloc((size_t)n * sizeof(float));
    int*   counts = (int*)alloc((size_t)n * sizeof(int));
    int*   rowst  = (int*)alloc((size_t)(n + 1) * sizeof(int));
    int*   bsums  = (int*)alloc(1024 * sizeof(int));
    int*   esrc   = (int*)alloc((size_t)E * sizeof(int));
    int*   rank   = (int*)alloc((size_t)E * sizeof(int));
    float* facc   = (float*)alloc(64 * sizeof(float));

    // ---- CSR build (once; graph shared across layers) ----
    zero_int_kernel<<<(n + 255) / 256, 256, 0, stream>>>(counts, n);
    zero_float_kernel<<<1, 64, 0, stream>>>(facc, 32);
    count_rank_kernel<<<2048, 256, 0, stream>>>(dstp, E, counts, rank);
    int nb = (n + 1023) / 1024;
    scan_phase1<<<nb, 1024, 0, stream>>>(counts, n, rowst, bsums);
    scan_phase2<<<1, 1024, 0, stream>>>(bsums, nb);
    scan_phase3<<<(n + 255) / 256, 256, 0, stream>>>(rowst, bsums, n, E);
    fill_kernel<<<2048, 256, 0, stream>>>(srcp, dstp, rank, E, rowst, esrc);

    // ---- layer 1: 64 -> 64 (ReLU folded into layer-2 gemm load) ----
    gemm_att_kernel<64, 64, false><<<(n + 63) / 64, BLOCK, 0, stream>>>(x, W1, as1, ad1, A, ssrc, sdst, n);
    gat_aggr_kernel<64, 2, true><<<(n + 3) / 4, BLOCK, 0, stream>>>(A, ssrc, sdst, rowst, esrc, b1, B, n);

    // ---- layer 2: 64 -> 32 (ReLU folded into layer-3 gemm load) ----
    gemm_att_kernel<64, 32, true><<<(n + 127) / 128, BLOCK, 0, stream>>>(B, W2, as2, ad2, A, ssrc, sdst, n);
    gat_aggr_kernel<32, 4, true><<<(n + 7) / 8, BLOCK, 0, stream>>>(A, ssrc, sdst, rowst, esrc, b2, B, n);

    // ---- layer 3: 32 -> 32, then global mean ----
    gemm_att_kernel<32, 32, true><<<(n + 127) / 128, BLOCK, 0, stream>>>(B, W3, as3, ad3, A, ssrc, sdst, n);
    gat_aggr_kernel<32, 4, false><<<(n + 7) / 8, BLOCK, 0, stream>>>(A, ssrc, sdst, rowst, esrc, nullptr, B, n);
    mean_kernel<<<1024, 256, 0, stream>>>(B, facc, n);
    finalize_kernel<<<1, 64, 0, stream>>>(facc, b3, tdp, cansup, (float*)d_out, n);
}

// Round 5
// 318.810 us; speedup vs baseline: 1.6607x; 1.0124x over previous
//
#include <hip/hip_runtime.h>

// 3-layer GAT (PyG GATConv) on MI355X.
// CSR build: count_rank (padded 64B-stride counters; atomicAdd returns
// in-bucket rank) -> scan -> fill (pure scatter, no atomics).
// Per layer: gemm_att (micro-tiled LDS GEMM, 4x4 register tile) -> gat_aggr
// (node-parallel fused softmax + gather-FMA; edge stash in LDS, pass-3 reads
// it back via broadcast ds_read_b128 — no per-edge shuffles).

constexpr int BLOCK = 256;
constexpr int CPAD = 16;  // counter stride in ints (64 B) to spread atomic lines

__device__ __forceinline__ float llrelu(float x) { return x >= 0.f ? x : 0.2f * x; }

__global__ void zero_strided_kernel(int* __restrict__ p, int count) {
    int i = blockIdx.x * blockDim.x + threadIdx.x;
    int stride = gridDim.x * blockDim.x;
    for (; i < count; i += stride) p[(size_t)i * CPAD] = 0;
}

__global__ void zero_float_kernel(float* __restrict__ p, int count) {
    int i = blockIdx.x * blockDim.x + threadIdx.x;
    if (i < count) p[i] = 0.f;
}

// counts[d*CPAD]++ per edge; the atomic's return value IS the edge's rank
// within its dst bucket. Padding gives each node its own 64B line.
__global__ void count_rank_kernel(const int* __restrict__ dst, int E,
                                  int* __restrict__ counts, int* __restrict__ rank) {
    int i = blockIdx.x * blockDim.x + threadIdx.x;
    int stride = gridDim.x * blockDim.x;
    for (; i < E; i += stride) rank[i] = atomicAdd(&counts[(size_t)dst[i] * CPAD], 1);
}

__global__ void scan_phase1(const int* __restrict__ counts, int n,
                            int* __restrict__ excl, int* __restrict__ block_sums) {
    __shared__ int s[1024];
    int tid = threadIdx.x;
    int gid = blockIdx.x * 1024 + tid;
    int v = (gid < n) ? counts[(size_t)gid * CPAD] : 0;
    s[tid] = v;
    for (int off = 1; off < 1024; off <<= 1) {
        __syncthreads();
        int t = (tid >= off) ? s[tid - off] : 0;
        __syncthreads();
        s[tid] += t;
    }
    __syncthreads();
    if (gid < n) excl[gid] = s[tid] - v;
    if (tid == 1023) block_sums[blockIdx.x] = s[tid];
}

__global__ void scan_phase2(int* __restrict__ block_sums, int nb) {
    __shared__ int s[1024];
    int tid = threadIdx.x;
    int v = (tid < nb) ? block_sums[tid] : 0;
    s[tid] = v;
    for (int off = 1; off < 1024; off <<= 1) {
        __syncthreads();
        int t = (tid >= off) ? s[tid - off] : 0;
        __syncthreads();
        s[tid] += t;
    }
    __syncthreads();
    if (tid < nb) block_sums[tid] = s[tid] - v;  // exclusive
}

__global__ void scan_phase3(int* __restrict__ row_start, const int* __restrict__ block_sums,
                            int n, int E) {
    int gid = blockIdx.x * blockDim.x + threadIdx.x;
    if (gid < n) row_start[gid] += block_sums[gid >> 10];
    if (gid == 0) row_start[n] = E;
}

// Pure scatter: slot = row_start[dst] + rank. No atomics, single 4B payload.
__global__ void fill_kernel(const int* __restrict__ src, const int* __restrict__ dst,
                            const int* __restrict__ rank, int E,
                            const int* __restrict__ row_start, int* __restrict__ esrc) {
    int i = blockIdx.x * blockDim.x + threadIdx.x;
    int stride = gridDim.x * blockDim.x;
    for (; i < E; i += stride) esrc[row_start[dst[i]] + rank[i]] = src[i];
}

// H = relu?(X) @ W, plus fused attention dots Ssrc = H.a_src, Sdst = H.a_dst.
// Micro-tiled: each thread owns a 4-node x 4-col register tile; X tile and W
// staged in LDS once per block, read via ds_read_b128. X rows padded to
// FIN+4 floats (16B-aligned, spreads the 4-row broadcast across bank groups).
template <int FIN, int FOUT, bool RELU_IN>
__global__ void gemm_att_kernel(const float* __restrict__ X, const float* __restrict__ W,
                                const float* __restrict__ asrc, const float* __restrict__ adst,
                                float* __restrict__ H, float* __restrict__ Ssrc,
                                float* __restrict__ Sdst, int n) {
    constexpr int CG = FOUT / 4;    // column groups (threads per node-row set)
    constexpr int NG = BLOCK / CG;  // node groups
    constexpr int TN = NG * 4;      // nodes per block
    constexpr int S = FIN + 4;      // padded LDS row stride (floats)
    __shared__ float Xs[TN * S];
    __shared__ float Ws[FIN * FOUT];

    int tid = threadIdx.x;
    int n0_blk = blockIdx.x * TN;

    // stage W (unpadded row-major, matches global layout)
    for (int t = tid; t < FIN * FOUT / 4; t += BLOCK) {
        float4 v = ((const float4*)W)[t];
        *(float4*)&Ws[t * 4] = v;
    }
    // stage X tile (clamp out-of-range rows to keep addresses valid)
    constexpr int RW = FIN / 4;  // float4 per row
    for (int t = tid; t < TN * RW; t += BLOCK) {
        int r = t / RW, c = t % RW;
        int gr = n0_blk + r;
        if (gr >= n) gr = n - 1;
        float4 v = ((const float4*)(X + (size_t)gr * FIN))[c];
        if (RELU_IN) {
            v.x = fmaxf(v.x, 0.f); v.y = fmaxf(v.y, 0.f);
            v.z = fmaxf(v.z, 0.f); v.w = fmaxf(v.w, 0.f);
        }
        *(float4*)&Xs[r * S + c * 4] = v;
    }
    __syncthreads();

    int tx = tid % CG;       // column group
    int ty = tid / CG;       // node group
    int c0 = tx * 4;
    int nloc = ty * 4;

    float acc[4][4];
#pragma unroll
    for (int i = 0; i < 4; ++i)
#pragma unroll
        for (int j = 0; j < 4; ++j) acc[i][j] = 0.f;

#pragma unroll 2
    for (int kc = 0; kc < FIN / 4; ++kc) {
        float4 xv[4], wv[4];
#pragma unroll
        for (int i = 0; i < 4; ++i) xv[i] = *(const float4*)&Xs[(nloc + i) * S + kc * 4];
#pragma unroll
        for (int kk = 0; kk < 4; ++kk) wv[kk] = *(const float4*)&Ws[(kc * 4 + kk) * FOUT + c0];
#pragma unroll
        for (int i = 0; i < 4; ++i) {
            float xi0 = xv[i].x, xi1 = xv[i].y, xi2 = xv[i].z, xi3 = xv[i].w;
            acc[i][0] = fmaf(xi0, wv[0].x, acc[i][0]);
            acc[i][1] = fmaf(xi0, wv[0].y, acc[i][1]);
            acc[i][2] = fmaf(xi0, wv[0].z, acc[i][2]);
            acc[i][3] = fmaf(xi0, wv[0].w, acc[i][3]);
            acc[i][0] = fmaf(xi1, wv[1].x, acc[i][0]);
            acc[i][1] = fmaf(xi1, wv[1].y, acc[i][1]);
            acc[i][2] = fmaf(xi1, wv[1].z, acc[i][2]);
            acc[i][3] = fmaf(xi1, wv[1].w, acc[i][3]);
            acc[i][0] = fmaf(xi2, wv[2].x, acc[i][0]);
            acc[i][1] = fmaf(xi2, wv[2].y, acc[i][1]);
            acc[i][2] = fmaf(xi2, wv[2].z, acc[i][2]);
            acc[i][3] = fmaf(xi2, wv[2].w, acc[i][3]);
            acc[i][0] = fmaf(xi3, wv[3].x, acc[i][0]);
            acc[i][1] = fmaf(xi3, wv[3].y, acc[i][1]);
            acc[i][2] = fmaf(xi3, wv[3].z, acc[i][2]);
            acc[i][3] = fmaf(xi3, wv[3].w, acc[i][3]);
        }
    }

    float4 as4 = *(const float4*)&asrc[c0];
    float4 ad4 = *(const float4*)&adst[c0];

#pragma unroll
    for (int i = 0; i < 4; ++i) {
        int node = n0_blk + nloc + i;
        bool ok = node < n;
        if (ok) {
            float4 hv = make_float4(acc[i][0], acc[i][1], acc[i][2], acc[i][3]);
            *(float4*)&H[(size_t)node * FOUT + c0] = hv;
        }
        float vs = acc[i][0] * as4.x + acc[i][1] * as4.y + acc[i][2] * as4.z + acc[i][3] * as4.w;
        float vd = acc[i][0] * ad4.x + acc[i][1] * ad4.y + acc[i][2] * ad4.z + acc[i][3] * ad4.w;
#pragma unroll
        for (int off = CG / 2; off > 0; off >>= 1) {
            vs += __shfl_xor(vs, off, CG);
            vd += __shfl_xor(vd, off, CG);
        }
        if (tx == 0 && ok) {
            Ssrc[node] = vs;
            Sdst[node] = vd;
        }
    }
}

// Node-parallel fused softmax + aggregation. One F-lane group per node.
// Edge stash lives in LDS: pass1 writes the precomputed H-row offset (s*F),
// pass2 writes exp(logit); pass3 reads 8 slots at a time via same-address
// (broadcast) ds_read_b128 — 4 LDS instructions per 8 edges instead of 16
// ds_bpermutes. Stash is pre-initialized to (w=0, idx=node*F) so full
// 8-batches are always safe (0-weighted L1-hit loads past deg).
// Overflow rows (deg > K*F) take a correct recompute path.
template <int F, int K, bool WITH_BIAS>
__global__ void gat_aggr_kernel(const float* __restrict__ H, const float* __restrict__ Ssrc,
                                const float* __restrict__ Sdst, const int* __restrict__ row_start,
                                const int* __restrict__ esrc, const float* __restrict__ bias,
                                float* __restrict__ OUT, int n) {
    constexpr int GPB = BLOCK / F;  // groups per block
    constexpr int NS = K * F;       // stash slots per group
    __shared__ __align__(16) float wlds[GPB][NS];
    __shared__ __align__(16) int ilds[GPB][NS];

    int tid = threadIdx.x;
    int grp = tid / F;
    int lane = tid % F;
    int node = blockIdx.x * GPB + grp;
    if (node >= n) return;

    int rs = row_start[node];
    int deg = row_start[node + 1] - rs;
    float sdi = Sdst[node];
    float selft = llrelu(Ssrc[node] + sdi);

    float wreg[K];

    // init stash tail-safe: weight 0, index -> own row (valid address)
#pragma unroll
    for (int k = 0; k < K; ++k) {
        wlds[grp][k * F + lane] = 0.f;
        ilds[grp][k * F + lane] = node * F;
    }

    // pass 1: logits -> regs, H-row offsets -> LDS, running max
    float m = selft;
#pragma unroll
    for (int k = 0; k < K; ++k) {
        int j = k * F + lane;
        if (j < deg) {
            int s = esrc[rs + j];
            float t = llrelu(Ssrc[s] + sdi);
            ilds[grp][j] = s * F;
            wreg[k] = t;
            m = fmaxf(m, t);
        }
    }
    for (int j = NS + lane; j < deg; j += F)  // overflow (deg > K*F): rare
        m = fmaxf(m, llrelu(Ssrc[esrc[rs + j]] + sdi));
#pragma unroll
    for (int off = F / 2; off > 0; off >>= 1) m = fmaxf(m, __shfl_xor(m, off, F));

    // pass 2: exp -> LDS, running sum
    float selfw = __expf(selft - m);
    float l = (lane == 0) ? selfw : 0.f;
#pragma unroll
    for (int k = 0; k < K; ++k) {
        int j = k * F + lane;
        if (j < deg) {
            float e = __expf(wreg[k] - m);
            wlds[grp][j] = e;
            l += e;
        }
    }
    for (int j = NS + lane; j < deg; j += F)
        l += __expf(llrelu(Ssrc[esrc[rs + j]] + sdi) - m);
#pragma unroll
    for (int off = F / 2; off > 0; off >>= 1) l += __shfl_xor(l, off, F);
    float winv = 1.f / l;

    // pass 3: acc = sum_j w_j * H[idx_j + lane]; 8 gathers in flight per batch
    float acc = selfw * H[(size_t)node * F + lane];
    int nb = deg < NS ? deg : NS;
    for (int j0 = 0; j0 < nb; j0 += 8) {
        float4 w0 = *(const float4*)&wlds[grp][j0];
        float4 w1 = *(const float4*)&wlds[grp][j0 + 4];
        int4 i0 = *(const int4*)&ilds[grp][j0];
        int4 i1 = *(const int4*)&ilds[grp][j0 + 4];
        int ix[8] = {i0.x, i0.y, i0.z, i0.w, i1.x, i1.y, i1.z, i1.w};
        float wv[8] = {w0.x, w0.y, w0.z, w0.w, w1.x, w1.y, w1.z, w1.w};
        float hv[8];
#pragma unroll
        for (int u = 0; u < 8; ++u) hv[u] = H[(size_t)(unsigned)(ix[u] + lane)];
#pragma unroll
        for (int u = 0; u < 8; ++u) acc = fmaf(wv[u], hv[u], acc);
    }
    for (int j = NS; j < deg; ++j) {  // overflow: all lanes recompute w_j
        int s = esrc[rs + j];
        float wj = __expf(llrelu(Ssrc[s] + sdi) - m);
        acc = fmaf(wj, H[(size_t)s * F + lane], acc);
    }

    acc *= winv;
    if (WITH_BIAS) acc += bias[lane];
    OUT[(size_t)node * F + lane] = acc;
}

// Sum OUT3 over nodes into facc[32].
__global__ void mean_kernel(const float* __restrict__ B, float* __restrict__ facc, int n) {
    __shared__ float s[32];
    int lane = threadIdx.x & 31, row = threadIdx.x >> 5;
    float a = 0.f;
    for (int node = blockIdx.x * 8 + row; node < n; node += gridDim.x * 8)
        a += B[(size_t)node * 32 + lane];
    if (threadIdx.x < 32) s[threadIdx.x] = 0.f;
    __syncthreads();
    atomicAdd(&s[lane], a);
    __syncthreads();
    if (threadIdx.x < 32) atomicAdd(&facc[threadIdx.x], s[threadIdx.x]);
}

__global__ void finalize_kernel(const float* __restrict__ facc, const float* __restrict__ b,
                                const float* __restrict__ tdp, const float* __restrict__ cansup,
                                float* __restrict__ out, int n) {
    int f = threadIdx.x;
    if (f < 32) {
        float td = tdp[0] * cansup[0];
        out[f] = (facc[f] / (float)n + b[f]) * td;
    }
}

extern "C" void kernel_launch(void* const* d_in, const int* in_sizes, int n_in,
                              void* d_out, int out_size, void* d_ws, size_t ws_size,
                              hipStream_t stream) {
    const float* x      = (const float*)d_in[0];
    const int* eidx     = (const int*)d_in[1];
    const float* W1     = (const float*)d_in[2];
    const float* as1    = (const float*)d_in[3];
    const float* ad1    = (const float*)d_in[4];
    const float* b1     = (const float*)d_in[5];
    const float* W2     = (const float*)d_in[6];
    const float* as2    = (const float*)d_in[7];
    const float* ad2    = (const float*)d_in[8];
    const float* b2     = (const float*)d_in[9];
    const float* W3     = (const float*)d_in[10];
    const float* as3    = (const float*)d_in[11];
    const float* ad3    = (const float*)d_in[12];
    const float* b3     = (const float*)d_in[13];
    const float* tdp    = (const float*)d_in[14];
    const float* cansup = (const float*)d_in[15];

    const int n = in_sizes[0] / 64;   // 100000 nodes
    const int E = in_sizes[1] / 2;    // 1600000 edges
    const int* srcp = eidx;
    const int* dstp = eidx + E;

    char* ws = (char*)d_ws;
    size_t off = 0;
    auto alloc = [&](size_t bytes) -> void* {
        void* p = ws + off;
        off += (bytes + 255) & ~(size_t)255;
        return p;
    };
    float* A      = (float*)alloc((size_t)n * 64 * sizeof(float));  // H
    float* B      = (float*)alloc((size_t)n * 64 * sizeof(float));  // layer out
    float* ssrc   = (float*)alloc((size_t)n * sizeof(float));
    float* sdst   = (float*)alloc((size_t)n * sizeof(float));
    int*   counts = (int*)alloc((size_t)n * CPAD * sizeof(int));    // padded
    int*   rowst  = (int*)alloc((size_t)(n + 1) * sizeof(int));
    int*   bsums  = (int*)alloc(1024 * sizeof(int));
    int*   esrc   = (int*)alloc((size_t)E * sizeof(int));
    int*   rank   = (int*)alloc((size_t)E * sizeof(int));
    float* facc   = (float*)alloc(64 * sizeof(float));

    // ---- CSR build (once; graph shared across layers) ----
    zero_strided_kernel<<<(n + 255) / 256, 256, 0, stream>>>(counts, n);
    zero_float_kernel<<<1, 64, 0, stream>>>(facc, 32);
    count_rank_kernel<<<2048, 256, 0, stream>>>(dstp, E, counts, rank);
    int nb = (n + 1023) / 1024;
    scan_phase1<<<nb, 1024, 0, stream>>>(counts, n, rowst, bsums);
    scan_phase2<<<1, 1024, 0, stream>>>(bsums, nb);
    scan_phase3<<<(n + 255) / 256, 256, 0, stream>>>(rowst, bsums, n, E);
    fill_kernel<<<2048, 256, 0, stream>>>(srcp, dstp, rank, E, rowst, esrc);

    // ---- layer 1: 64 -> 64 (ReLU folded into layer-2 gemm load) ----
    gemm_att_kernel<64, 64, false><<<(n + 63) / 64, BLOCK, 0, stream>>>(x, W1, as1, ad1, A, ssrc, sdst, n);
    gat_aggr_kernel<64, 2, true><<<(n + 3) / 4, BLOCK, 0, stream>>>(A, ssrc, sdst, rowst, esrc, b1, B, n);

    // ---- layer 2: 64 -> 32 (ReLU folded into layer-3 gemm load) ----
    gemm_att_kernel<64, 32, true><<<(n + 127) / 128, BLOCK, 0, stream>>>(B, W2, as2, ad2, A, ssrc, sdst, n);
    gat_aggr_kernel<32, 4, true><<<(n + 7) / 8, BLOCK, 0, stream>>>(A, ssrc, sdst, rowst, esrc, b2, B, n);

    // ---- layer 3: 32 -> 32, then global mean ----
    gemm_att_kernel<32, 32, true><<<(n + 127) / 128, BLOCK, 0, stream>>>(B, W3, as3, ad3, A, ssrc, sdst, n);
    gat_aggr_kernel<32, 4, false><<<(n + 7) / 8, BLOCK, 0, stream>>>(A, ssrc, sdst, rowst, esrc, nullptr, B, n);
    mean_kernel<<<1024, 256, 0, stream>>>(B, facc, n);
    finalize_kernel<<<1, 64, 0, stream>>>(facc, b3, tdp, cansup, (float*)d_out, n);
}

// Round 6
// 284.906 us; speedup vs baseline: 1.8584x; 1.1190x over previous
//
#include <hip/hip_runtime.h>

// 3-layer GAT (PyG GATConv) on MI355X.
// CSR build: count_rank (padded 64B-stride counters; atomicAdd returns
// in-bucket rank) -> scan -> fill (pure scatter, no atomics).
// Per layer: gemm_att (micro-tiled LDS GEMM, 4x4 register tile; epilogue
// emits H in bf16 (RNE) — H is consumed only by the gather) -> gat_aggr
// (node-parallel fused softmax + gather-FMA; LDS edge stash, broadcast
// ds_read_b128 readback, bf16 H gather at 2 B/element, f32 accumulation).

constexpr int BLOCK = 256;
constexpr int CPAD = 16;  // counter stride in ints (64 B) to spread atomic lines

__device__ __forceinline__ float llrelu(float x) { return x >= 0.f ? x : 0.2f * x; }

__device__ __forceinline__ unsigned short f2bf(float f) {
    unsigned int u = __float_as_uint(f);
    u += 0x7FFFu + ((u >> 16) & 1u);  // round-to-nearest-even
    return (unsigned short)(u >> 16);
}
__device__ __forceinline__ float bf2f(unsigned short h) {
    return __uint_as_float((unsigned int)h << 16);
}

__global__ void zero_strided_kernel(int* __restrict__ p, int count) {
    int i = blockIdx.x * blockDim.x + threadIdx.x;
    int stride = gridDim.x * blockDim.x;
    for (; i < count; i += stride) p[(size_t)i * CPAD] = 0;
}

__global__ void zero_float_kernel(float* __restrict__ p, int count) {
    int i = blockIdx.x * blockDim.x + threadIdx.x;
    if (i < count) p[i] = 0.f;
}

// counts[d*CPAD]++ per edge; the atomic's return value IS the edge's rank
// within its dst bucket. Padding gives each node its own 64B line.
__global__ void count_rank_kernel(const int* __restrict__ dst, int E,
                                  int* __restrict__ counts, int* __restrict__ rank) {
    int i = blockIdx.x * blockDim.x + threadIdx.x;
    int stride = gridDim.x * blockDim.x;
    for (; i < E; i += stride) rank[i] = atomicAdd(&counts[(size_t)dst[i] * CPAD], 1);
}

__global__ void scan_phase1(const int* __restrict__ counts, int n,
                            int* __restrict__ excl, int* __restrict__ block_sums) {
    __shared__ int s[1024];
    int tid = threadIdx.x;
    int gid = blockIdx.x * 1024 + tid;
    int v = (gid < n) ? counts[(size_t)gid * CPAD] : 0;
    s[tid] = v;
    for (int off = 1; off < 1024; off <<= 1) {
        __syncthreads();
        int t = (tid >= off) ? s[tid - off] : 0;
        __syncthreads();
        s[tid] += t;
    }
    __syncthreads();
    if (gid < n) excl[gid] = s[tid] - v;
    if (tid == 1023) block_sums[blockIdx.x] = s[tid];
}

__global__ void scan_phase2(int* __restrict__ block_sums, int nb) {
    __shared__ int s[1024];
    int tid = threadIdx.x;
    int v = (tid < nb) ? block_sums[tid] : 0;
    s[tid] = v;
    for (int off = 1; off < 1024; off <<= 1) {
        __syncthreads();
        int t = (tid >= off) ? s[tid - off] : 0;
        __syncthreads();
        s[tid] += t;
    }
    __syncthreads();
    if (tid < nb) block_sums[tid] = s[tid] - v;  // exclusive
}

__global__ void scan_phase3(int* __restrict__ row_start, const int* __restrict__ block_sums,
                            int n, int E) {
    int gid = blockIdx.x * blockDim.x + threadIdx.x;
    if (gid < n) row_start[gid] += block_sums[gid >> 10];
    if (gid == 0) row_start[n] = E;
}

// Pure scatter: slot = row_start[dst] + rank. No atomics, single 4B payload.
__global__ void fill_kernel(const int* __restrict__ src, const int* __restrict__ dst,
                            const int* __restrict__ rank, int E,
                            const int* __restrict__ row_start, int* __restrict__ esrc) {
    int i = blockIdx.x * blockDim.x + threadIdx.x;
    int stride = gridDim.x * blockDim.x;
    for (; i < E; i += stride) esrc[row_start[dst[i]] + rank[i]] = src[i];
}

// H(bf16) = relu?(X) @ W, plus attention dots Ssrc/Sdst from exact f32 accs.
// Micro-tiled: each thread owns a 4-node x 4-col register tile; X tile and W
// staged in LDS once per block, read via ds_read_b128. X rows padded to
// FIN+4 floats.
template <int FIN, int FOUT, bool RELU_IN>
__global__ void gemm_att_kernel(const float* __restrict__ X, const float* __restrict__ W,
                                const float* __restrict__ asrc, const float* __restrict__ adst,
                                unsigned short* __restrict__ H, float* __restrict__ Ssrc,
                                float* __restrict__ Sdst, int n) {
    constexpr int CG = FOUT / 4;    // column groups (threads per node-row set)
    constexpr int NG = BLOCK / CG;  // node groups
    constexpr int TN = NG * 4;      // nodes per block
    constexpr int S = FIN + 4;      // padded LDS row stride (floats)
    __shared__ float Xs[TN * S];
    __shared__ float Ws[FIN * FOUT];

    int tid = threadIdx.x;
    int n0_blk = blockIdx.x * TN;

    // stage W (unpadded row-major, matches global layout)
    for (int t = tid; t < FIN * FOUT / 4; t += BLOCK) {
        float4 v = ((const float4*)W)[t];
        *(float4*)&Ws[t * 4] = v;
    }
    // stage X tile (clamp out-of-range rows to keep addresses valid)
    constexpr int RW = FIN / 4;  // float4 per row
    for (int t = tid; t < TN * RW; t += BLOCK) {
        int r = t / RW, c = t % RW;
        int gr = n0_blk + r;
        if (gr >= n) gr = n - 1;
        float4 v = ((const float4*)(X + (size_t)gr * FIN))[c];
        if (RELU_IN) {
            v.x = fmaxf(v.x, 0.f); v.y = fmaxf(v.y, 0.f);
            v.z = fmaxf(v.z, 0.f); v.w = fmaxf(v.w, 0.f);
        }
        *(float4*)&Xs[r * S + c * 4] = v;
    }
    __syncthreads();

    int tx = tid % CG;       // column group
    int ty = tid / CG;       // node group
    int c0 = tx * 4;
    int nloc = ty * 4;

    float acc[4][4];
#pragma unroll
    for (int i = 0; i < 4; ++i)
#pragma unroll
        for (int j = 0; j < 4; ++j) acc[i][j] = 0.f;

#pragma unroll 2
    for (int kc = 0; kc < FIN / 4; ++kc) {
        float4 xv[4], wv[4];
#pragma unroll
        for (int i = 0; i < 4; ++i) xv[i] = *(const float4*)&Xs[(nloc + i) * S + kc * 4];
#pragma unroll
        for (int kk = 0; kk < 4; ++kk) wv[kk] = *(const float4*)&Ws[(kc * 4 + kk) * FOUT + c0];
#pragma unroll
        for (int i = 0; i < 4; ++i) {
            float xi0 = xv[i].x, xi1 = xv[i].y, xi2 = xv[i].z, xi3 = xv[i].w;
            acc[i][0] = fmaf(xi0, wv[0].x, acc[i][0]);
            acc[i][1] = fmaf(xi0, wv[0].y, acc[i][1]);
            acc[i][2] = fmaf(xi0, wv[0].z, acc[i][2]);
            acc[i][3] = fmaf(xi0, wv[0].w, acc[i][3]);
            acc[i][0] = fmaf(xi1, wv[1].x, acc[i][0]);
            acc[i][1] = fmaf(xi1, wv[1].y, acc[i][1]);
            acc[i][2] = fmaf(xi1, wv[1].z, acc[i][2]);
            acc[i][3] = fmaf(xi1, wv[1].w, acc[i][3]);
            acc[i][0] = fmaf(xi2, wv[2].x, acc[i][0]);
            acc[i][1] = fmaf(xi2, wv[2].y, acc[i][1]);
            acc[i][2] = fmaf(xi2, wv[2].z, acc[i][2]);
            acc[i][3] = fmaf(xi2, wv[2].w, acc[i][3]);
            acc[i][0] = fmaf(xi3, wv[3].x, acc[i][0]);
            acc[i][1] = fmaf(xi3, wv[3].y, acc[i][1]);
            acc[i][2] = fmaf(xi3, wv[3].z, acc[i][2]);
            acc[i][3] = fmaf(xi3, wv[3].w, acc[i][3]);
        }
    }

    float4 as4 = *(const float4*)&asrc[c0];
    float4 ad4 = *(const float4*)&adst[c0];

#pragma unroll
    for (int i = 0; i < 4; ++i) {
        int node = n0_blk + nloc + i;
        bool ok = node < n;
        if (ok) {
            ushort4 hb;
            hb.x = f2bf(acc[i][0]); hb.y = f2bf(acc[i][1]);
            hb.z = f2bf(acc[i][2]); hb.w = f2bf(acc[i][3]);
            *(ushort4*)&H[(size_t)node * FOUT + c0] = hb;
        }
        float vs = acc[i][0] * as4.x + acc[i][1] * as4.y + acc[i][2] * as4.z + acc[i][3] * as4.w;
        float vd = acc[i][0] * ad4.x + acc[i][1] * ad4.y + acc[i][2] * ad4.z + acc[i][3] * ad4.w;
#pragma unroll
        for (int off = CG / 2; off > 0; off >>= 1) {
            vs += __shfl_xor(vs, off, CG);
            vd += __shfl_xor(vd, off, CG);
        }
        if (tx == 0 && ok) {
            Ssrc[node] = vs;
            Sdst[node] = vd;
        }
    }
}

// Node-parallel fused softmax + aggregation over bf16 H. One F-lane group
// per node. LDS edge stash (H-row offsets + exp weights), pass-3 reads it
// back via broadcast ds_read_b128; 8 bf16 row-gathers in flight per batch;
// f32 accumulation. Stash pre-initialized tail-safe (w=0, idx=own row).
// Overflow rows (deg > K*F) take a correct recompute path.
template <int F, int K, bool WITH_BIAS>
__global__ void gat_aggr_kernel(const unsigned short* __restrict__ H,
                                const float* __restrict__ Ssrc,
                                const float* __restrict__ Sdst, const int* __restrict__ row_start,
                                const int* __restrict__ esrc, const float* __restrict__ bias,
                                float* __restrict__ OUT, int n) {
    constexpr int GPB = BLOCK / F;  // groups per block
    constexpr int NS = K * F;       // stash slots per group
    __shared__ __align__(16) float wlds[GPB][NS];
    __shared__ __align__(16) int ilds[GPB][NS];

    int tid = threadIdx.x;
    int grp = tid / F;
    int lane = tid % F;
    int node = blockIdx.x * GPB + grp;
    if (node >= n) return;

    int rs = row_start[node];
    int deg = row_start[node + 1] - rs;
    float sdi = Sdst[node];
    float selft = llrelu(Ssrc[node] + sdi);

    float wreg[K];

    // init stash tail-safe: weight 0, index -> own row (valid address)
#pragma unroll
    for (int k = 0; k < K; ++k) {
        wlds[grp][k * F + lane] = 0.f;
        ilds[grp][k * F + lane] = node * F;
    }

    // pass 1: logits -> regs, H-row offsets -> LDS, running max
    float m = selft;
#pragma unroll
    for (int k = 0; k < K; ++k) {
        int j = k * F + lane;
        if (j < deg) {
            int s = esrc[rs + j];
            float t = llrelu(Ssrc[s] + sdi);
            ilds[grp][j] = s * F;
            wreg[k] = t;
            m = fmaxf(m, t);
        }
    }
    for (int j = NS + lane; j < deg; j += F)  // overflow (deg > K*F): rare
        m = fmaxf(m, llrelu(Ssrc[esrc[rs + j]] + sdi));
#pragma unroll
    for (int off = F / 2; off > 0; off >>= 1) m = fmaxf(m, __shfl_xor(m, off, F));

    // pass 2: exp -> LDS, running sum
    float selfw = __expf(selft - m);
    float l = (lane == 0) ? selfw : 0.f;
#pragma unroll
    for (int k = 0; k < K; ++k) {
        int j = k * F + lane;
        if (j < deg) {
            float e = __expf(wreg[k] - m);
            wlds[grp][j] = e;
            l += e;
        }
    }
    for (int j = NS + lane; j < deg; j += F)
        l += __expf(llrelu(Ssrc[esrc[rs + j]] + sdi) - m);
#pragma unroll
    for (int off = F / 2; off > 0; off >>= 1) l += __shfl_xor(l, off, F);
    float winv = 1.f / l;

    // pass 3: acc = sum_j w_j * H[idx_j + lane]; 8 gathers in flight per batch
    float acc = selfw * bf2f(H[(size_t)node * F + lane]);
    int nb = deg < NS ? deg : NS;
    for (int j0 = 0; j0 < nb; j0 += 8) {
        float4 w0 = *(const float4*)&wlds[grp][j0];
        float4 w1 = *(const float4*)&wlds[grp][j0 + 4];
        int4 i0 = *(const int4*)&ilds[grp][j0];
        int4 i1 = *(const int4*)&ilds[grp][j0 + 4];
        int ix[8] = {i0.x, i0.y, i0.z, i0.w, i1.x, i1.y, i1.z, i1.w};
        float wv[8] = {w0.x, w0.y, w0.z, w0.w, w1.x, w1.y, w1.z, w1.w};
        unsigned short hv[8];
#pragma unroll
        for (int u = 0; u < 8; ++u) hv[u] = H[(size_t)(unsigned)(ix[u] + lane)];
#pragma unroll
        for (int u = 0; u < 8; ++u) acc = fmaf(wv[u], bf2f(hv[u]), acc);
    }
    for (int j = NS; j < deg; ++j) {  // overflow: all lanes recompute w_j
        int s = esrc[rs + j];
        float wj = __expf(llrelu(Ssrc[s] + sdi) - m);
        acc = fmaf(wj, bf2f(H[(size_t)s * F + lane]), acc);
    }

    acc *= winv;
    if (WITH_BIAS) acc += bias[lane];
    OUT[(size_t)node * F + lane] = acc;
}

// Sum OUT3 over nodes into facc[32].
__global__ void mean_kernel(const float* __restrict__ B, float* __restrict__ facc, int n) {
    __shared__ float s[32];
    int lane = threadIdx.x & 31, row = threadIdx.x >> 5;
    float a = 0.f;
    for (int node = blockIdx.x * 8 + row; node < n; node += gridDim.x * 8)
        a += B[(size_t)node * 32 + lane];
    if (threadIdx.x < 32) s[threadIdx.x] = 0.f;
    __syncthreads();
    atomicAdd(&s[lane], a);
    __syncthreads();
    if (threadIdx.x < 32) atomicAdd(&facc[threadIdx.x], s[threadIdx.x]);
}

__global__ void finalize_kernel(const float* __restrict__ facc, const float* __restrict__ b,
                                const float* __restrict__ tdp, const float* __restrict__ cansup,
                                float* __restrict__ out, int n) {
    int f = threadIdx.x;
    if (f < 32) {
        float td = tdp[0] * cansup[0];
        out[f] = (facc[f] / (float)n + b[f]) * td;
    }
}

extern "C" void kernel_launch(void* const* d_in, const int* in_sizes, int n_in,
                              void* d_out, int out_size, void* d_ws, size_t ws_size,
                              hipStream_t stream) {
    const float* x      = (const float*)d_in[0];
    const int* eidx     = (const int*)d_in[1];
    const float* W1     = (const float*)d_in[2];
    const float* as1    = (const float*)d_in[3];
    const float* ad1    = (const float*)d_in[4];
    const float* b1     = (const float*)d_in[5];
    const float* W2     = (const float*)d_in[6];
    const float* as2    = (const float*)d_in[7];
    const float* ad2    = (const float*)d_in[8];
    const float* b2     = (const float*)d_in[9];
    const float* W3     = (const float*)d_in[10];
    const float* as3    = (const float*)d_in[11];
    const float* ad3    = (const float*)d_in[12];
    const float* b3     = (const float*)d_in[13];
    const float* tdp    = (const float*)d_in[14];
    const float* cansup = (const float*)d_in[15];

    const int n = in_sizes[0] / 64;   // 100000 nodes
    const int E = in_sizes[1] / 2;    // 1600000 edges
    const int* srcp = eidx;
    const int* dstp = eidx + E;

    char* ws = (char*)d_ws;
    size_t off = 0;
    auto alloc = [&](size_t bytes) -> void* {
        void* p = ws + off;
        off += (bytes + 255) & ~(size_t)255;
        return p;
    };
    unsigned short* A = (unsigned short*)alloc((size_t)n * 64 * sizeof(unsigned short));  // H bf16
    float* B      = (float*)alloc((size_t)n * 64 * sizeof(float));  // layer out (f32)
    float* ssrc   = (float*)alloc((size_t)n * sizeof(float));
    float* sdst   = (float*)alloc((size_t)n * sizeof(float));
    int*   counts = (int*)alloc((size_t)n * CPAD * sizeof(int));    // padded
    int*   rowst  = (int*)alloc((size_t)(n + 1) * sizeof(int));
    int*   bsums  = (int*)alloc(1024 * sizeof(int));
    int*   esrc   = (int*)alloc((size_t)E * sizeof(int));
    int*   rank   = (int*)alloc((size_t)E * sizeof(int));
    float* facc   = (float*)alloc(64 * sizeof(float));

    // ---- CSR build (once; graph shared across layers) ----
    zero_strided_kernel<<<(n + 255) / 256, 256, 0, stream>>>(counts, n);
    zero_float_kernel<<<1, 64, 0, stream>>>(facc, 32);
    count_rank_kernel<<<2048, 256, 0, stream>>>(dstp, E, counts, rank);
    int nb = (n + 1023) / 1024;
    scan_phase1<<<nb, 1024, 0, stream>>>(counts, n, rowst, bsums);
    scan_phase2<<<1, 1024, 0, stream>>>(bsums, nb);
    scan_phase3<<<(n + 255) / 256, 256, 0, stream>>>(rowst, bsums, n, E);
    fill_kernel<<<2048, 256, 0, stream>>>(srcp, dstp, rank, E, rowst, esrc);

    // ---- layer 1: 64 -> 64 (ReLU folded into layer-2 gemm load) ----
    gemm_att_kernel<64, 64, false><<<(n + 63) / 64, BLOCK, 0, stream>>>(x, W1, as1, ad1, A, ssrc, sdst, n);
    gat_aggr_kernel<64, 2, true><<<(n + 3) / 4, BLOCK, 0, stream>>>(A, ssrc, sdst, rowst, esrc, b1, B, n);

    // ---- layer 2: 64 -> 32 (ReLU folded into layer-3 gemm load) ----
    gemm_att_kernel<64, 32, true><<<(n + 127) / 128, BLOCK, 0, stream>>>(B, W2, as2, ad2, A, ssrc, sdst, n);
    gat_aggr_kernel<32, 4, true><<<(n + 7) / 8, BLOCK, 0, stream>>>(A, ssrc, sdst, rowst, esrc, b2, B, n);

    // ---- layer 3: 32 -> 32, then global mean ----
    gemm_att_kernel<32, 32, true><<<(n + 127) / 128, BLOCK, 0, stream>>>(B, W3, as3, ad3, A, ssrc, sdst, n);
    gat_aggr_kernel<32, 4, false><<<(n + 7) / 8, BLOCK, 0, stream>>>(A, ssrc, sdst, rowst, esrc, nullptr, B, n);
    mean_kernel<<<1024, 256, 0, stream>>>(B, facc, n);
    finalize_kernel<<<1, 64, 0, stream>>>(facc, b3, tdp, cansup, (float*)d_out, n);
}

// Round 7
// 260.188 us; speedup vs baseline: 2.0349x; 1.0950x over previous
//
#include <hip/hip_runtime.h>

// 3-layer GAT (PyG GATConv) on MI355X.
// CSR build: count_rank (padded 64B-stride counters; atomicAdd returns
// in-bucket rank) FUSED with layer-1 GEMM (heterogeneous blocks: latency-
// bound atomic blocks overlap VALU-bound GEMM blocks on the same CUs)
// -> scan -> fill (pure scatter, no atomics).
// Per layer: gemm_att (micro-tiled LDS GEMM, 4x4 register tile; epilogue
// emits H in bf16) -> gat_aggr (node-parallel fused softmax + gather-FMA;
// LDS edge stash, broadcast ds_read_b128 readback, 16 bf16 row-gathers in
// flight per group, f32 accumulation).

constexpr int BLOCK = 256;
constexpr int CPAD = 16;    // counter stride in ints (64 B) to spread atomic lines
constexpr int NCOUNT = 2048;  // count blocks in the fused kernel

__device__ __forceinline__ float llrelu(float x) { return x >= 0.f ? x : 0.2f * x; }

__device__ __forceinline__ unsigned short f2bf(float f) {
    unsigned int u = __float_as_uint(f);
    u += 0x7FFFu + ((u >> 16) & 1u);  // round-to-nearest-even
    return (unsigned short)(u >> 16);
}
__device__ __forceinline__ float bf2f(unsigned short h) {
    return __uint_as_float((unsigned int)h << 16);
}

__global__ void zero_strided_kernel(int* __restrict__ p, int count) {
    int i = blockIdx.x * blockDim.x + threadIdx.x;
    int stride = gridDim.x * blockDim.x;
    for (; i < count; i += stride) p[(size_t)i * CPAD] = 0;
}

__global__ void scan_phase1(const int* __restrict__ counts, int n,
                            int* __restrict__ excl, int* __restrict__ block_sums) {
    __shared__ int s[1024];
    int tid = threadIdx.x;
    int gid = blockIdx.x * 1024 + tid;
    int v = (gid < n) ? counts[(size_t)gid * CPAD] : 0;
    s[tid] = v;
    for (int off = 1; off < 1024; off <<= 1) {
        __syncthreads();
        int t = (tid >= off) ? s[tid - off] : 0;
        __syncthreads();
        s[tid] += t;
    }
    __syncthreads();
    if (gid < n) excl[gid] = s[tid] - v;
    if (tid == 1023) block_sums[blockIdx.x] = s[tid];
}

__global__ void scan_phase2(int* __restrict__ block_sums, int nb) {
    __shared__ int s[1024];
    int tid = threadIdx.x;
    int v = (tid < nb) ? block_sums[tid] : 0;
    s[tid] = v;
    for (int off = 1; off < 1024; off <<= 1) {
        __syncthreads();
        int t = (tid >= off) ? s[tid - off] : 0;
        __syncthreads();
        s[tid] += t;
    }
    __syncthreads();
    if (tid < nb) block_sums[tid] = s[tid] - v;  // exclusive
}

__global__ void scan_phase3(int* __restrict__ row_start, const int* __restrict__ block_sums,
                            int n, int E) {
    int gid = blockIdx.x * blockDim.x + threadIdx.x;
    if (gid < n) row_start[gid] += block_sums[gid >> 10];
    if (gid == 0) row_start[n] = E;
}

// Pure scatter: slot = row_start[dst] + rank. No atomics, single 4B payload.
__global__ void fill_kernel(const int* __restrict__ src, const int* __restrict__ dst,
                            const int* __restrict__ rank, int E,
                            const int* __restrict__ row_start, int* __restrict__ esrc) {
    int i = blockIdx.x * blockDim.x + threadIdx.x;
    int stride = gridDim.x * blockDim.x;
    for (; i < E; i += stride) esrc[row_start[dst[i]] + rank[i]] = src[i];
}

// GEMM body shared by the standalone and fused kernels.
// H(bf16) = relu?(X) @ W, plus attention dots Ssrc/Sdst from exact f32 accs.
template <int FIN, int FOUT, bool RELU_IN>
__device__ __forceinline__ void gemm_att_body(
    const float* __restrict__ X, const float* __restrict__ W,
    const float* __restrict__ asrc, const float* __restrict__ adst,
    unsigned short* __restrict__ H, float* __restrict__ Ssrc,
    float* __restrict__ Sdst, int n, int gblk) {
    constexpr int CG = FOUT / 4;    // column groups (threads per node-row set)
    constexpr int NG = BLOCK / CG;  // node groups
    constexpr int TN = NG * 4;      // nodes per block
    constexpr int S = FIN + 4;      // padded LDS row stride (floats)
    __shared__ float Xs[TN * S];
    __shared__ float Ws[FIN * FOUT];

    int tid = threadIdx.x;
    int n0_blk = gblk * TN;

    // stage W (unpadded row-major, matches global layout)
    for (int t = tid; t < FIN * FOUT / 4; t += BLOCK) {
        float4 v = ((const float4*)W)[t];
        *(float4*)&Ws[t * 4] = v;
    }
    // stage X tile (clamp out-of-range rows to keep addresses valid)
    constexpr int RW = FIN / 4;  // float4 per row
    for (int t = tid; t < TN * RW; t += BLOCK) {
        int r = t / RW, c = t % RW;
        int gr = n0_blk + r;
        if (gr >= n) gr = n - 1;
        float4 v = ((const float4*)(X + (size_t)gr * FIN))[c];
        if (RELU_IN) {
            v.x = fmaxf(v.x, 0.f); v.y = fmaxf(v.y, 0.f);
            v.z = fmaxf(v.z, 0.f); v.w = fmaxf(v.w, 0.f);
        }
        *(float4*)&Xs[r * S + c * 4] = v;
    }
    __syncthreads();

    int tx = tid % CG;       // column group
    int ty = tid / CG;       // node group
    int c0 = tx * 4;
    int nloc = ty * 4;

    float acc[4][4];
#pragma unroll
    for (int i = 0; i < 4; ++i)
#pragma unroll
        for (int j = 0; j < 4; ++j) acc[i][j] = 0.f;

#pragma unroll 2
    for (int kc = 0; kc < FIN / 4; ++kc) {
        float4 xv[4], wv[4];
#pragma unroll
        for (int i = 0; i < 4; ++i) xv[i] = *(const float4*)&Xs[(nloc + i) * S + kc * 4];
#pragma unroll
        for (int kk = 0; kk < 4; ++kk) wv[kk] = *(const float4*)&Ws[(kc * 4 + kk) * FOUT + c0];
#pragma unroll
        for (int i = 0; i < 4; ++i) {
            float xi0 = xv[i].x, xi1 = xv[i].y, xi2 = xv[i].z, xi3 = xv[i].w;
            acc[i][0] = fmaf(xi0, wv[0].x, acc[i][0]);
            acc[i][1] = fmaf(xi0, wv[0].y, acc[i][1]);
            acc[i][2] = fmaf(xi0, wv[0].z, acc[i][2]);
            acc[i][3] = fmaf(xi0, wv[0].w, acc[i][3]);
            acc[i][0] = fmaf(xi1, wv[1].x, acc[i][0]);
            acc[i][1] = fmaf(xi1, wv[1].y, acc[i][1]);
            acc[i][2] = fmaf(xi1, wv[1].z, acc[i][2]);
            acc[i][3] = fmaf(xi1, wv[1].w, acc[i][3]);
            acc[i][0] = fmaf(xi2, wv[2].x, acc[i][0]);
            acc[i][1] = fmaf(xi2, wv[2].y, acc[i][1]);
            acc[i][2] = fmaf(xi2, wv[2].z, acc[i][2]);
            acc[i][3] = fmaf(xi2, wv[2].w, acc[i][3]);
            acc[i][0] = fmaf(xi3, wv[3].x, acc[i][0]);
            acc[i][1] = fmaf(xi3, wv[3].y, acc[i][1]);
            acc[i][2] = fmaf(xi3, wv[3].z, acc[i][2]);
            acc[i][3] = fmaf(xi3, wv[3].w, acc[i][3]);
        }
    }

    float4 as4 = *(const float4*)&asrc[c0];
    float4 ad4 = *(const float4*)&adst[c0];

#pragma unroll
    for (int i = 0; i < 4; ++i) {
        int node = n0_blk + nloc + i;
        bool ok = node < n;
        if (ok) {
            ushort4 hb;
            hb.x = f2bf(acc[i][0]); hb.y = f2bf(acc[i][1]);
            hb.z = f2bf(acc[i][2]); hb.w = f2bf(acc[i][3]);
            *(ushort4*)&H[(size_t)node * FOUT + c0] = hb;
        }
        float vs = acc[i][0] * as4.x + acc[i][1] * as4.y + acc[i][2] * as4.z + acc[i][3] * as4.w;
        float vd = acc[i][0] * ad4.x + acc[i][1] * ad4.y + acc[i][2] * ad4.z + acc[i][3] * ad4.w;
#pragma unroll
        for (int off = CG / 2; off > 0; off >>= 1) {
            vs += __shfl_xor(vs, off, CG);
            vd += __shfl_xor(vd, off, CG);
        }
        if (tx == 0 && ok) {
            Ssrc[node] = vs;
            Sdst[node] = vd;
        }
    }
}

template <int FIN, int FOUT, bool RELU_IN>
__global__ void gemm_att_kernel(const float* __restrict__ X, const float* __restrict__ W,
                                const float* __restrict__ asrc, const float* __restrict__ adst,
                                unsigned short* __restrict__ H, float* __restrict__ Ssrc,
                                float* __restrict__ Sdst, int n) {
    gemm_att_body<FIN, FOUT, RELU_IN>(X, W, asrc, adst, H, Ssrc, Sdst, n, blockIdx.x);
}

// Fused layer-1 GEMM + count_rank (+ facc zero). Even blocks run the GEMM,
// odd blocks run the atomic counting loop — interleaved so latency-bound
// atomic waves and VALU-bound GEMM waves co-resident on every CU.
template <int FIN, int FOUT>
__global__ void gemm_att_count_kernel(const float* __restrict__ X, const float* __restrict__ W,
                                      const float* __restrict__ asrc, const float* __restrict__ adst,
                                      unsigned short* __restrict__ H, float* __restrict__ Ssrc,
                                      float* __restrict__ Sdst, int n, int ngemm,
                                      const int* __restrict__ dst, int E,
                                      int* __restrict__ counts, int* __restrict__ rank,
                                      float* __restrict__ facc) {
    int bid = blockIdx.x;
    if ((bid & 1) == 0) {
        int gb = bid >> 1;
        if (gb >= ngemm) return;
        gemm_att_body<FIN, FOUT, false>(X, W, asrc, adst, H, Ssrc, Sdst, n, gb);
    } else {
        int cb = bid >> 1;  // 0 .. NCOUNT-1
        if (cb == 0 && threadIdx.x < 32) facc[threadIdx.x] = 0.f;
        int i = cb * BLOCK + threadIdx.x;
        int stride = NCOUNT * BLOCK;
        for (; i < E; i += stride) rank[i] = atomicAdd(&counts[(size_t)dst[i] * CPAD], 1);
    }
}

// Node-parallel fused softmax + aggregation over bf16 H. One F-lane group
// per node. LDS edge stash (H-row offsets + exp weights), pass-3 reads it
// back via broadcast ds_read_b128; 16 bf16 row-gathers in flight per batch;
// f32 accumulation. Stash pre-initialized tail-safe (w=0, idx=own row).
// Overflow rows (deg > K*F) take a correct recompute path.
template <int F, int K, bool WITH_BIAS>
__global__ void gat_aggr_kernel(const unsigned short* __restrict__ H,
                                const float* __restrict__ Ssrc,
                                const float* __restrict__ Sdst, const int* __restrict__ row_start,
                                const int* __restrict__ esrc, const float* __restrict__ bias,
                                float* __restrict__ OUT, int n) {
    constexpr int GPB = BLOCK / F;  // groups per block
    constexpr int NS = K * F;       // stash slots per group (multiple of 16)
    __shared__ __align__(16) float wlds[GPB][NS];
    __shared__ __align__(16) int ilds[GPB][NS];

    int tid = threadIdx.x;
    int grp = tid / F;
    int lane = tid % F;
    int node = blockIdx.x * GPB + grp;
    if (node >= n) return;

    int rs = row_start[node];
    int deg = row_start[node + 1] - rs;
    float sdi = Sdst[node];
    float selft = llrelu(Ssrc[node] + sdi);

    float wreg[K];

    // init stash tail-safe: weight 0, index -> own row (valid address)
#pragma unroll
    for (int k = 0; k < K; ++k) {
        wlds[grp][k * F + lane] = 0.f;
        ilds[grp][k * F + lane] = node * F;
    }

    // pass 1: logits -> regs, H-row offsets -> LDS, running max
    float m = selft;
#pragma unroll
    for (int k = 0; k < K; ++k) {
        int j = k * F + lane;
        if (j < deg) {
            int s = esrc[rs + j];
            float t = llrelu(Ssrc[s] + sdi);
            ilds[grp][j] = s * F;
            wreg[k] = t;
            m = fmaxf(m, t);
        }
    }
    for (int j = NS + lane; j < deg; j += F)  // overflow (deg > K*F): rare
        m = fmaxf(m, llrelu(Ssrc[esrc[rs + j]] + sdi));
#pragma unroll
    for (int off = F / 2; off > 0; off >>= 1) m = fmaxf(m, __shfl_xor(m, off, F));

    // pass 2: exp -> LDS, running sum
    float selfw = __expf(selft - m);
    float l = (lane == 0) ? selfw : 0.f;
#pragma unroll
    for (int k = 0; k < K; ++k) {
        int j = k * F + lane;
        if (j < deg) {
            float e = __expf(wreg[k] - m);
            wlds[grp][j] = e;
            l += e;
        }
    }
    for (int j = NS + lane; j < deg; j += F)
        l += __expf(llrelu(Ssrc[esrc[rs + j]] + sdi) - m);
#pragma unroll
    for (int off = F / 2; off > 0; off >>= 1) l += __shfl_xor(l, off, F);
    float winv = 1.f / l;

    // pass 3: acc = sum_j w_j * H[idx_j + lane]; 16 gathers in flight/batch.
    // Reads run to the next multiple of 16 — always within NS (stash padded).
    float acc = selfw * bf2f(H[(size_t)node * F + lane]);
    int nb = deg < NS ? deg : NS;
    for (int j0 = 0; j0 < nb; j0 += 16) {
        float4 w0 = *(const float4*)&wlds[grp][j0];
        float4 w1 = *(const float4*)&wlds[grp][j0 + 4];
        float4 w2 = *(const float4*)&wlds[grp][j0 + 8];
        float4 w3 = *(const float4*)&wlds[grp][j0 + 12];
        int4 i0 = *(const int4*)&ilds[grp][j0];
        int4 i1 = *(const int4*)&ilds[grp][j0 + 4];
        int4 i2 = *(const int4*)&ilds[grp][j0 + 8];
        int4 i3 = *(const int4*)&ilds[grp][j0 + 12];
        int ix[16] = {i0.x, i0.y, i0.z, i0.w, i1.x, i1.y, i1.z, i1.w,
                      i2.x, i2.y, i2.z, i2.w, i3.x, i3.y, i3.z, i3.w};
        float wv[16] = {w0.x, w0.y, w0.z, w0.w, w1.x, w1.y, w1.z, w1.w,
                        w2.x, w2.y, w2.z, w2.w, w3.x, w3.y, w3.z, w3.w};
        unsigned short hv[16];
#pragma unroll
        for (int u = 0; u < 16; ++u) hv[u] = H[(size_t)(unsigned)(ix[u] + lane)];
#pragma unroll
        for (int u = 0; u < 16; ++u) acc = fmaf(wv[u], bf2f(hv[u]), acc);
    }
    for (int j = NS; j < deg; ++j) {  // overflow: all lanes recompute w_j
        int s = esrc[rs + j];
        float wj = __expf(llrelu(Ssrc[s] + sdi) - m);
        acc = fmaf(wj, bf2f(H[(size_t)s * F + lane]), acc);
    }

    acc *= winv;
    if (WITH_BIAS) acc += bias[lane];
    OUT[(size_t)node * F + lane] = acc;
}

// Sum OUT3 over nodes into facc[32].
__global__ void mean_kernel(const float* __restrict__ B, float* __restrict__ facc, int n) {
    __shared__ float s[32];
    int lane = threadIdx.x & 31, row = threadIdx.x >> 5;
    float a = 0.f;
    for (int node = blockIdx.x * 8 + row; node < n; node += gridDim.x * 8)
        a += B[(size_t)node * 32 + lane];
    if (threadIdx.x < 32) s[threadIdx.x] = 0.f;
    __syncthreads();
    atomicAdd(&s[lane], a);
    __syncthreads();
    if (threadIdx.x < 32) atomicAdd(&facc[threadIdx.x], s[threadIdx.x]);
}

__global__ void finalize_kernel(const float* __restrict__ facc, const float* __restrict__ b,
                                const float* __restrict__ tdp, const float* __restrict__ cansup,
                                float* __restrict__ out, int n) {
    int f = threadIdx.x;
    if (f < 32) {
        float td = tdp[0] * cansup[0];
        out[f] = (facc[f] / (float)n + b[f]) * td;
    }
}

extern "C" void kernel_launch(void* const* d_in, const int* in_sizes, int n_in,
                              void* d_out, int out_size, void* d_ws, size_t ws_size,
                              hipStream_t stream) {
    const float* x      = (const float*)d_in[0];
    const int* eidx     = (const int*)d_in[1];
    const float* W1     = (const float*)d_in[2];
    const float* as1    = (const float*)d_in[3];
    const float* ad1    = (const float*)d_in[4];
    const float* b1     = (const float*)d_in[5];
    const float* W2     = (const float*)d_in[6];
    const float* as2    = (const float*)d_in[7];
    const float* ad2    = (const float*)d_in[8];
    const float* b2     = (const float*)d_in[9];
    const float* W3     = (const float*)d_in[10];
    const float* as3    = (const float*)d_in[11];
    const float* ad3    = (const float*)d_in[12];
    const float* b3     = (const float*)d_in[13];
    const float* tdp    = (const float*)d_in[14];
    const float* cansup = (const float*)d_in[15];

    const int n = in_sizes[0] / 64;   // 100000 nodes
    const int E = in_sizes[1] / 2;    // 1600000 edges
    const int* srcp = eidx;
    const int* dstp = eidx + E;

    char* ws = (char*)d_ws;
    size_t off = 0;
    auto alloc = [&](size_t bytes) -> void* {
        void* p = ws + off;
        off += (bytes + 255) & ~(size_t)255;
        return p;
    };
    unsigned short* A = (unsigned short*)alloc((size_t)n * 64 * sizeof(unsigned short));  // H bf16
    float* B      = (float*)alloc((size_t)n * 64 * sizeof(float));  // layer out (f32)
    float* ssrc   = (float*)alloc((size_t)n * sizeof(float));
    float* sdst   = (float*)alloc((size_t)n * sizeof(float));
    int*   counts = (int*)alloc((size_t)n * CPAD * sizeof(int));    // padded
    int*   rowst  = (int*)alloc((size_t)(n + 1) * sizeof(int));
    int*   bsums  = (int*)alloc(1024 * sizeof(int));
    int*   esrc   = (int*)alloc((size_t)E * sizeof(int));
    int*   rank   = (int*)alloc((size_t)E * sizeof(int));
    float* facc   = (float*)alloc(64 * sizeof(float));

    // ---- CSR build overlapped with layer-1 GEMM ----
    zero_strided_kernel<<<(n + 255) / 256, 256, 0, stream>>>(counts, n);
    const int ngemm1 = (n + 63) / 64;
    gemm_att_count_kernel<64, 64><<<2 * NCOUNT, BLOCK, 0, stream>>>(
        x, W1, as1, ad1, A, ssrc, sdst, n, ngemm1, dstp, E, counts, rank, facc);
    int nb = (n + 1023) / 1024;
    scan_phase1<<<nb, 1024, 0, stream>>>(counts, n, rowst, bsums);
    scan_phase2<<<1, 1024, 0, stream>>>(bsums, nb);
    scan_phase3<<<(n + 255) / 256, 256, 0, stream>>>(rowst, bsums, n, E);
    fill_kernel<<<2048, 256, 0, stream>>>(srcp, dstp, rank, E, rowst, esrc);

    // ---- layer 1 aggregation ----
    gat_aggr_kernel<64, 2, true><<<(n + 3) / 4, BLOCK, 0, stream>>>(A, ssrc, sdst, rowst, esrc, b1, B, n);

    // ---- layer 2: 64 -> 32 (ReLU folded into layer-3 gemm load) ----
    gemm_att_kernel<64, 32, true><<<(n + 127) / 128, BLOCK, 0, stream>>>(B, W2, as2, ad2, A, ssrc, sdst, n);
    gat_aggr_kernel<32, 4, true><<<(n + 7) / 8, BLOCK, 0, stream>>>(A, ssrc, sdst, rowst, esrc, b2, B, n);

    // ---- layer 3: 32 -> 32, then global mean ----
    gemm_att_kernel<32, 32, true><<<(n + 127) / 128, BLOCK, 0, stream>>>(B, W3, as3, ad3, A, ssrc, sdst, n);
    gat_aggr_kernel<32, 4, false><<<(n + 7) / 8, BLOCK, 0, stream>>>(A, ssrc, sdst, rowst, esrc, nullptr, B, n);
    mean_kernel<<<1024, 256, 0, stream>>>(B, facc, n);
    finalize_kernel<<<1, 64, 0, stream>>>(facc, b3, tdp, cansup, (float*)d_out, n);
}